// Round 9
// baseline (349.712 us; speedup 1.0000x reference)
//
#include <hip/hip_runtime.h>

#define N_NODES   50000
#define M_PAD     50048            // 782 * 64
#define N_EDGES   800000
#define HID       128
#define OUT_DIM   64
#define NUM_GRAPHS 512
#define EPS       1e-6f
#define SCAN_NB   ((N_NODES + 255) / 256)   // 196
#define FILL_RANGE 6250            // N_NODES / 8
#define FILL_CHUNK4 2048           // 8192 edges per chunk / 4
#define FILL_CHUNKS 98             // ceil(800000 / 8192)

typedef __attribute__((ext_vector_type(8))) short short8;
typedef __attribute__((ext_vector_type(4))) float f32x4;

static __device__ __forceinline__ unsigned short f2bf(float f) {
    unsigned u = __builtin_bit_cast(unsigned, f);
    u += 0x7FFFu + ((u >> 16) & 1u);           // round-to-nearest-even
    return (unsigned short)(u >> 16);
}
static __device__ __forceinline__ float bf2f(unsigned short h) {
    unsigned u = ((unsigned)h) << 16;
    return __builtin_bit_cast(float, u);
}

static __device__ __forceinline__ float signpow(float x, bool sqrt_mode) {
    if (x == 0.0f) return 0.0f;
    float a = fabsf(x) + EPS;
    float v = sqrt_mode ? sqrtf(a) : a * a;
    return x > 0.0f ? v : -v;
}

// ---- CSR build ------------------------------------------------------------
__global__ void k_count(const int* __restrict__ ei, int* __restrict__ cnt) {
    int i4 = blockIdx.x * blockDim.x + threadIdx.x;
    if (i4 * 4 >= N_EDGES) return;
    uint4 d = ((const uint4*)(ei + N_EDGES))[i4];
    atomicAdd(&cnt[d.x], 1);
    atomicAdd(&cnt[d.y], 1);
    atomicAdd(&cnt[d.z], 1);
    atomicAdd(&cnt[d.w], 1);
}

__global__ __launch_bounds__(256) void k_scan_part(const int* __restrict__ cnt,
                                                   int* __restrict__ bsum) {
    __shared__ int sm[256];
    int t = threadIdx.x, i = blockIdx.x * 256 + t;
    sm[t] = (i < N_NODES) ? cnt[i] : 0;
    __syncthreads();
    for (int off = 128; off > 0; off >>= 1) {
        if (t < off) sm[t] += sm[t + off];
        __syncthreads();
    }
    if (t == 0) bsum[blockIdx.x] = sm[0];
}

__global__ __launch_bounds__(256) void k_scan_base(const int* __restrict__ bsum,
                                                   int* __restrict__ bbase) {
    __shared__ int sm[256];
    int t = threadIdx.x;
    int v = (t < SCAN_NB) ? bsum[t] : 0;
    sm[t] = v;
    __syncthreads();
    for (int off = 1; off < 256; off <<= 1) {
        int u = (t >= off) ? sm[t - off] : 0;
        __syncthreads();
        sm[t] += u;
        __syncthreads();
    }
    if (t < SCAN_NB) bbase[t] = sm[t] - v;   // exclusive
}

__global__ __launch_bounds__(256) void k_scan_final(const int* __restrict__ cnt,
                                                    const int* __restrict__ bbase,
                                                    int* __restrict__ offs,
                                                    float* __restrict__ dis) {
    __shared__ int sm[256];
    int t = threadIdx.x, i = blockIdx.x * 256 + t;
    int c = (i < N_NODES) ? cnt[i] : 0;
    sm[t] = c;
    __syncthreads();
    for (int off = 1; off < 256; off <<= 1) {
        int u = (t >= off) ? sm[t - off] : 0;
        __syncthreads();
        sm[t] += u;
        __syncthreads();
    }
    if (i < N_NODES) {
        offs[i] = bbase[blockIdx.x] + sm[t] - c;
        dis[i]  = rsqrtf((float)c + 1.0f);
    }
    if (blockIdx.x == 0 && t == 0) offs[N_NODES] = N_EDGES;
}

// dst-range-partitioned fill: block (chunk, r=bid&7) fills only dsts in range r.
// Reuses cnt as a countdown slot allocator (cnt is dead after scan_final).
__global__ __launch_bounds__(256) void k_fill(const int* __restrict__ ei,
                                              const int* __restrict__ offs,
                                              int* __restrict__ cntdown,
                                              int* __restrict__ csr) {
    int r     = blockIdx.x & 7;
    int chunk = blockIdx.x >> 3;
    int lo = r * FILL_RANGE, hi = lo + FILL_RANGE;   // last range covers tail (8*6250=50000)
    const uint4* src4 = (const uint4*)ei;
    const uint4* dst4 = (const uint4*)(ei + N_EDGES);
    int base4 = chunk * FILL_CHUNK4;
    #pragma unroll 1
    for (int b = 0; b < 8; b++) {
        int i4 = base4 + b * 256 + threadIdx.x;
        if (i4 >= N_EDGES / 4) break;
        uint4 d = dst4[i4];
        uint4 s = src4[i4];
        int dd[4] = {(int)d.x, (int)d.y, (int)d.z, (int)d.w};
        int ss[4] = {(int)s.x, (int)s.y, (int)s.z, (int)s.w};
        #pragma unroll
        for (int k = 0; k < 4; k++) {
            if (dd[k] >= lo && dd[k] < hi) {
                int p = atomicSub(&cntdown[dd[k]], 1);
                csr[offs[dd[k]] + p - 1] = ss[k];
            }
        }
    }
}

// ---- split fp32 -> (bf16 hi, bf16 lo) -------------------------------------
__global__ void k_split(const float* __restrict__ in, short* __restrict__ hi,
                        short* __restrict__ lo, int n4) {
    int i = blockIdx.x * blockDim.x + threadIdx.x;
    if (i >= n4) return;
    float4 v = ((const float4*)in)[i];
    unsigned short h0 = f2bf(v.x), h1 = f2bf(v.y), h2 = f2bf(v.z), h3 = f2bf(v.w);
    unsigned short l0 = f2bf(v.x - bf2f(h0)), l1 = f2bf(v.y - bf2f(h1));
    unsigned short l2 = f2bf(v.z - bf2f(h2)), l3 = f2bf(v.w - bf2f(h3));
    ushort4 vh; vh.x = h0; vh.y = h1; vh.z = h2; vh.w = h3;
    ushort4 vl; vl.x = l0; vl.y = l1; vl.z = l2; vl.w = l3;
    ((ushort4*)hi)[i] = vh;
    ((ushort4*)lo)[i] = vl;
}

// ---- all three W[128k x 128n] -> W^T splits [3][128n][128k] hi/lo ----------
__global__ void k_wsplit3(const float* __restrict__ W0, const float* __restrict__ W1,
                          const float* __restrict__ W2, short* __restrict__ Wth,
                          short* __restrict__ Wtl) {
    int which = blockIdx.y;
    const float* W = which == 0 ? W0 : (which == 1 ? W1 : W2);
    int tid = blockIdx.x * blockDim.x + threadIdx.x;   // 16384
    int k = tid & 127, n = tid >> 7;
    float w = W[k * HID + n];
    unsigned short h = f2bf(w);
    Wth[which * HID * HID + n * HID + k] = (short)h;
    Wtl[which * HID * HID + n * HID + k] = (short)f2bf(w - bf2f(h));
}

// ---- MFMA GEMM: (A @ W) * scale[row] -> bf16 hi/lo pair --------------------
__global__ __launch_bounds__(256) void k_gemm_mfma(const short* __restrict__ Ah,
                                                   const short* __restrict__ Al,
                                                   const short* __restrict__ Wh,
                                                   const short* __restrict__ Wl,
                                                   unsigned short* __restrict__ th,
                                                   unsigned short* __restrict__ tl,
                                                   int M,
                                                   const float* __restrict__ scale) {
    int wid  = threadIdx.x >> 6;
    int lane = threadIdx.x & 63;
    int row0 = blockIdx.x * 64 + wid * 16;
    int r    = lane & 15;
    int ko   = (lane >> 4) * 8;

    const short* Arh = Ah + (size_t)(row0 + r) * HID;
    const short* Arl = Al + (size_t)(row0 + r) * HID;
    short8 afh[4], afl[4];
    #pragma unroll
    for (int c = 0; c < 4; c++) {
        afh[c] = *(const short8*)(Arh + c * 32 + ko);
        afl[c] = *(const short8*)(Arl + c * 32 + ko);
    }

    f32x4 acc[8];
    #pragma unroll
    for (int n = 0; n < 8; n++) acc[n] = (f32x4){0.f, 0.f, 0.f, 0.f};

    #pragma unroll
    for (int n = 0; n < 8; n++) {
        const short* Wrh = Wh + (size_t)(n * 16 + r) * HID;
        const short* Wrl = Wl + (size_t)(n * 16 + r) * HID;
        #pragma unroll
        for (int c = 0; c < 4; c++) {
            short8 bh = *(const short8*)(Wrh + c * 32 + ko);
            short8 bl = *(const short8*)(Wrl + c * 32 + ko);
            acc[n] = __builtin_amdgcn_mfma_f32_16x16x32_bf16(afh[c], bh, acc[n], 0, 0, 0);
            acc[n] = __builtin_amdgcn_mfma_f32_16x16x32_bf16(afl[c], bh, acc[n], 0, 0, 0);
            acc[n] = __builtin_amdgcn_mfma_f32_16x16x32_bf16(afh[c], bl, acc[n], 0, 0, 0);
        }
    }

    int crow = row0 + (lane >> 4) * 4;
    #pragma unroll
    for (int q = 0; q < 4; q++) {
        int gr = crow + q;
        if (gr < M) {
            float s = scale[gr];
            #pragma unroll
            for (int n = 0; n < 8; n++) {
                float v = acc[n][q] * s;
                unsigned short hi = f2bf(v);
                unsigned short lo = f2bf(v - bf2f(hi));
                th[(size_t)gr * HID + n * 16 + (lane & 15)] = hi;
                tl[(size_t)gr * HID + n * 16 + (lane & 15)] = lo;
            }
        }
    }
}

// ---- GCN aggregation: gather bf16-hi rows; self term = hi+lo (exact) -------
__global__ __launch_bounds__(256) void k_agg(const unsigned short* __restrict__ th,
                                             const unsigned short* __restrict__ tl,
                                             const int* __restrict__ offs,
                                             const int* __restrict__ csr_src,
                                             const float* __restrict__ dis,
                                             const float* __restrict__ bias,
                                             float* __restrict__ hout,
                                             short* __restrict__ hh,
                                             short* __restrict__ hl,
                                             int mode) {
    int node = blockIdx.x * 4 + (threadIdx.x >> 6);
    if (node >= N_NODES) return;
    int lane = threadIdx.x & 63;
    int c  = lane & 31;          // col group: cols [c*4, c*4+4)
    int e  = lane >> 5;          // edge slot 0/1
    int beg = offs[node], end = offs[node + 1];
    float dn = dis[node];

    float ax[4] = {}, ay[4] = {}, az[4] = {}, aw[4] = {};
    for (int j = beg; j < end; j += 8) {
        #pragma unroll
        for (int k = 0; k < 4; k++) {
            int jj = j + k * 2 + e;
            int jc = jj < end ? jj : end - 1;
            int s = csr_src[jc];
            float m = (jj < end) ? 1.0f : 0.0f;
            uint2 v = *(const uint2*)&th[(size_t)s * HID + c * 4];
            float v0 = __builtin_bit_cast(float, v.x << 16);
            float v1 = __builtin_bit_cast(float, v.x & 0xFFFF0000u);
            float v2 = __builtin_bit_cast(float, v.y << 16);
            float v3 = __builtin_bit_cast(float, v.y & 0xFFFF0000u);
            ax[k] = fmaf(v0, m, ax[k]);
            ay[k] = fmaf(v1, m, ay[k]);
            az[k] = fmaf(v2, m, az[k]);
            aw[k] = fmaf(v3, m, aw[k]);
        }
    }
    float tx = (ax[0] + ax[1]) + (ax[2] + ax[3]);
    float ty = (ay[0] + ay[1]) + (ay[2] + ay[3]);
    float tz = (az[0] + az[1]) + (az[2] + az[3]);
    float tw = (aw[0] + aw[1]) + (aw[2] + aw[3]);
    tx += __shfl_xor(tx, 32);
    ty += __shfl_xor(ty, 32);
    tz += __shfl_xor(tz, 32);
    tw += __shfl_xor(tw, 32);

    if (e == 0) {
        ushort4 sh = *(const ushort4*)&th[(size_t)node * HID + c * 4];
        ushort4 sl = *(const ushort4*)&tl[(size_t)node * HID + c * 4];
        float4 b4  = *(const float4*)&bias[c * 4];
        float ox = (tx + bf2f(sh.x) + bf2f(sl.x)) * dn + b4.x;
        float oy = (ty + bf2f(sh.y) + bf2f(sl.y)) * dn + b4.y;
        float oz = (tz + bf2f(sh.z) + bf2f(sl.z)) * dn + b4.z;
        float ow = (tw + bf2f(sh.w) + bf2f(sl.w)) * dn + b4.w;
        if (mode == 1) {
            ox = fmaxf(ox, 0.f); oy = fmaxf(oy, 0.f);
            oz = fmaxf(oz, 0.f); ow = fmaxf(ow, 0.f);
            unsigned short hx = f2bf(ox), hy = f2bf(oy), hz = f2bf(oz), hw = f2bf(ow);
            ushort4 vh; vh.x = hx; vh.y = hy; vh.z = hz; vh.w = hw;
            ushort4 vl;
            vl.x = f2bf(ox - bf2f(hx)); vl.y = f2bf(oy - bf2f(hy));
            vl.z = f2bf(oz - bf2f(hz)); vl.w = f2bf(ow - bf2f(hw));
            *(ushort4*)&hh[(size_t)node * HID + c * 4] = vh;
            *(ushort4*)&hl[(size_t)node * HID + c * 4] = vl;
        } else {
            float4 o = make_float4(ox, oy, oz, ow);
            *(float4*)&hout[(size_t)node * HID + c * 4] = o;
        }
    }
}

// ---- graph boundaries from sorted batch ------------------------------------
__global__ void k_bounds(const int* __restrict__ batch, int* __restrict__ gstart) {
    int n = blockIdx.x * blockDim.x + threadIdx.x;
    if (n >= N_NODES) return;
    int b  = batch[n];
    int bp = (n == 0) ? -1 : batch[n - 1];
    for (int g = bp + 1; g <= b; g++) gstart[g] = n;
    if (n == N_NODES - 1)
        for (int g = b + 1; g <= NUM_GRAPHS; g++) gstart[g] = N_NODES;
}

// ---- generalized-mean pool: one block (256t) per graph ----------------------
__global__ __launch_bounds__(256) void k_pool(const float* __restrict__ h,
                                              const int* __restrict__ gstart,
                                              float* __restrict__ pooled) {
    __shared__ float smx[4][64], smy[4][64];
    int g = blockIdx.x;
    int t = threadIdx.x;
    int c = t & 63;          // col group (2 floats)
    int slot = t >> 6;       // 0..3
    int beg = gstart[g], end = gstart[g + 1];

    float sx = 0.f, sy = 0.f;
    for (int n = beg + slot; n < end; n += 4) {
        float2 v = *(const float2*)&h[(size_t)n * HID + c * 2];
        sx += signpow(v.x, false);
        sy += signpow(v.y, false);
    }
    smx[slot][c] = sx; smy[slot][c] = sy;
    __syncthreads();
    if (slot == 0) {
        sx = (smx[0][c] + smx[1][c]) + (smx[2][c] + smx[3][c]);
        sy = (smy[0][c] + smy[1][c]) + (smy[2][c] + smy[3][c]);
        float cnt = fmaxf((float)(end - beg), 1.0f);
        float px = sx / cnt, py = sy / cnt;
        pooled[g * HID + c * 2]     = fmaxf(signpow(px, true), 0.f);
        pooled[g * HID + c * 2 + 1] = fmaxf(signpow(py, true), 0.f);
    }
}

// ---- FF head ---------------------------------------------------------------
__global__ __launch_bounds__(128) void k_ff(const float* __restrict__ pooled,
                                            const float* __restrict__ Wf0,
                                            const float* __restrict__ bf0,
                                            const float* __restrict__ Wf1,
                                            const float* __restrict__ bf1,
                                            float* __restrict__ out) {
    __shared__ float row[128];
    __shared__ float zrow[128];
    int g = blockIdx.x, t = threadIdx.x;
    row[t] = pooled[g * HID + t];
    __syncthreads();
    float acc = bf0[t];
    #pragma unroll 8
    for (int k = 0; k < 128; k++) acc = fmaf(row[k], Wf0[k * 128 + t], acc);
    zrow[t] = fmaxf(acc, 0.f);
    __syncthreads();
    if (t < OUT_DIM) {
        float a2 = bf1[t];
        #pragma unroll 8
        for (int k = 0; k < 128; k++) a2 = fmaf(zrow[k], Wf1[k * OUT_DIM + t], a2);
        out[g * OUT_DIM + t] = a2;
    }
}

// ---------------------------------------------------------------------------
static inline size_t align256(size_t x) { return (x + 255) & ~(size_t)255; }

extern "C" void kernel_launch(void* const* d_in, const int* in_sizes, int n_in,
                              void* d_out, int out_size, void* d_ws, size_t ws_size,
                              hipStream_t stream) {
    const float* x     = (const float*)d_in[0];
    const int*   ei    = (const int*)d_in[1];
    const int*   batch = (const int*)d_in[2];
    const float* W0  = (const float*)d_in[3];  const float* b0  = (const float*)d_in[4];
    const float* W1  = (const float*)d_in[5];  const float* b1  = (const float*)d_in[6];
    const float* W2  = (const float*)d_in[7];  const float* b2  = (const float*)d_in[8];
    const float* Wf0 = (const float*)d_in[9];  const float* bf0 = (const float*)d_in[10];
    const float* Wf1 = (const float*)d_in[11]; const float* bf1 = (const float*)d_in[12];
    float* out = (float*)d_out;

    char* p = (char*)d_ws;
    unsigned short* th = (unsigned short*)p; p += align256((size_t)M_PAD * HID * 2);
    unsigned short* tl = (unsigned short*)p; p += align256((size_t)M_PAD * HID * 2);
    short* bufAh = (short*)p; p += align256((size_t)M_PAD * HID * 2);
    short* bufAl = (short*)p; p += align256((size_t)M_PAD * HID * 2);
    short* bufBh = (short*)p; p += align256((size_t)M_PAD * HID * 2);
    short* bufBl = (short*)p; p += align256((size_t)M_PAD * HID * 2);
    float* h     = (float*)bufBh;   // aliases bufBh+bufBl (contiguous), live only after layer2
    int*   cnt     = (int*)p;   p += align256((size_t)N_NODES * 4);
    int*   offs    = (int*)p;   p += align256((size_t)(N_NODES + 1) * 4);
    int*   csr     = (int*)p;   p += align256((size_t)N_EDGES * 4);
    float* dis     = (float*)p; p += align256((size_t)N_NODES * 4);
    int*   gstart  = (int*)p;   p += align256((size_t)(NUM_GRAPHS + 1) * 4);
    float* pooled  = (float*)p; p += align256((size_t)NUM_GRAPHS * HID * 4);
    int*   bsum    = (int*)p;   p += align256((size_t)SCAN_NB * 4);
    int*   bbase   = (int*)p;   p += align256((size_t)SCAN_NB * 4);
    short* Wth     = (short*)p; p += align256((size_t)3 * HID * HID * 2);
    short* Wtl     = (short*)p; p += align256((size_t)3 * HID * HID * 2);

    hipMemsetAsync(cnt, 0, (size_t)N_NODES * 4, stream);

    const int TB = 256;
    k_count<<<(N_EDGES / 4 + TB - 1) / TB, TB, 0, stream>>>(ei, cnt);
    k_scan_part <<<SCAN_NB, 256, 0, stream>>>(cnt, bsum);
    k_scan_base <<<1, 256, 0, stream>>>(bsum, bbase);
    k_scan_final<<<SCAN_NB, 256, 0, stream>>>(cnt, bbase, offs, dis);
    k_fill<<<FILL_CHUNKS * 8, 256, 0, stream>>>(ei, offs, cnt, csr);

    // splits
    int n4 = N_NODES * HID / 4;
    k_split<<<(n4 + TB - 1) / TB, TB, 0, stream>>>(x, bufAh, bufAl, n4);
    dim3 wg(64, 3);
    k_wsplit3<<<wg, 256, 0, stream>>>(W0, W1, W2, Wth, Wtl);

    int gemm_blocks = M_PAD / 64;             // 782
    int agg_blocks  = (N_NODES + 3) / 4;

    // layer 0
    k_gemm_mfma<<<gemm_blocks, 256, 0, stream>>>(bufAh, bufAl, Wth, Wtl,
                                                 th, tl, N_NODES, dis);
    k_agg<<<agg_blocks, 256, 0, stream>>>(th, tl, offs, csr, dis, b0,
                                          nullptr, bufBh, bufBl, 1);
    // layer 1
    k_gemm_mfma<<<gemm_blocks, 256, 0, stream>>>(bufBh, bufBl, Wth + HID * HID, Wtl + HID * HID,
                                                 th, tl, N_NODES, dis);
    k_agg<<<agg_blocks, 256, 0, stream>>>(th, tl, offs, csr, dis, b1,
                                          nullptr, bufAh, bufAl, 1);
    // layer 2 (no relu, fp32 out for pooling)
    k_gemm_mfma<<<gemm_blocks, 256, 0, stream>>>(bufAh, bufAl, Wth + 2 * HID * HID, Wtl + 2 * HID * HID,
                                                 th, tl, N_NODES, dis);
    k_agg<<<agg_blocks, 256, 0, stream>>>(th, tl, offs, csr, dis, b2,
                                          h, nullptr, nullptr, 0);

    k_bounds<<<(N_NODES + TB - 1) / TB, TB, 0, stream>>>(batch, gstart);
    k_pool<<<NUM_GRAPHS, 256, 0, stream>>>(h, gstart, pooled);
    k_ff<<<NUM_GRAPHS, 128, 0, stream>>>(pooled, Wf0, bf0, Wf1, bf1, out);
}

// Round 10
// 289.980 us; speedup vs baseline: 1.2060x; 1.2060x over previous
//
#include <hip/hip_runtime.h>

#define N_NODES   50000
#define M_PAD     50048            // 782 * 64
#define N_EDGES   800000
#define HID       128
#define OUT_DIM   64
#define NUM_GRAPHS 512
#define EPS       1e-6f
#define NBUCK     196              // buckets of 256 nodes: ceil(50000/256)
#define BUCKCAP   6144             // >> max bucket load (~4400)
#define ABLOCKS   98               // pass-A blocks, 8192 edges each

typedef __attribute__((ext_vector_type(8))) short short8;
typedef __attribute__((ext_vector_type(4))) float f32x4;

static __device__ __forceinline__ unsigned short f2bf(float f) {
    unsigned u = __builtin_bit_cast(unsigned, f);
    u += 0x7FFFu + ((u >> 16) & 1u);           // round-to-nearest-even
    return (unsigned short)(u >> 16);
}
static __device__ __forceinline__ float bf2f(unsigned short h) {
    unsigned u = ((unsigned)h) << 16;
    return __builtin_bit_cast(float, u);
}

static __device__ __forceinline__ float signpow(float x, bool sqrt_mode) {
    if (x == 0.0f) return 0.0f;
    float a = fabsf(x) + EPS;
    float v = sqrt_mode ? sqrtf(a) : a * a;
    return x > 0.0f ? v : -v;
}

// ---- CSR build, pass A: bucket edges by dst>>8 -----------------------------
// ebuf[b*BUCKCAP + i] = src | (dst<<16)  (both < 65536)
__global__ __launch_bounds__(256) void k_bucketize(const int* __restrict__ ei,
                                                   int* __restrict__ gcnt,
                                                   unsigned* __restrict__ ebuf) {
    __shared__ int lcnt[NBUCK];
    __shared__ int lbase[NBUCK];
    int tid = threadIdx.x;
    for (int i = tid; i < NBUCK; i += 256) lcnt[i] = 0;
    __syncthreads();

    const uint4* src4 = (const uint4*)ei;
    const uint4* dst4 = (const uint4*)(ei + N_EDGES);
    int base4 = blockIdx.x * 2048;

    // pass 1: local histogram
    #pragma unroll 1
    for (int it = 0; it < 8; it++) {
        int i4 = base4 + it * 256 + tid;
        if (i4 < N_EDGES / 4) {
            uint4 d = dst4[i4];
            atomicAdd(&lcnt[d.x >> 8], 1);
            atomicAdd(&lcnt[d.y >> 8], 1);
            atomicAdd(&lcnt[d.z >> 8], 1);
            atomicAdd(&lcnt[d.w >> 8], 1);
        }
    }
    __syncthreads();
    for (int i = tid; i < NBUCK; i += 256) {
        lbase[i] = atomicAdd(&gcnt[i], lcnt[i]);
        lcnt[i] = 0;
    }
    __syncthreads();

    // pass 2: place
    #pragma unroll 1
    for (int it = 0; it < 8; it++) {
        int i4 = base4 + it * 256 + tid;
        if (i4 < N_EDGES / 4) {
            uint4 d = dst4[i4];
            uint4 s = src4[i4];
            unsigned dd[4] = {d.x, d.y, d.z, d.w};
            unsigned ss[4] = {s.x, s.y, s.z, s.w};
            #pragma unroll
            for (int k = 0; k < 4; k++) {
                int b = dd[k] >> 8;
                int p = atomicAdd(&lcnt[b], 1);
                ebuf[(size_t)b * BUCKCAP + lbase[b] + p] = ss[k] | (dd[k] << 16);
            }
        }
    }
}

// ---- pass A2: exclusive scan of bucket counts ------------------------------
__global__ __launch_bounds__(256) void k_bscan(const int* __restrict__ gcnt,
                                               int* __restrict__ bbase,
                                               int* __restrict__ offs) {
    __shared__ int sm[256];
    int t = threadIdx.x;
    int v = (t < NBUCK) ? gcnt[t] : 0;
    sm[t] = v;
    __syncthreads();
    for (int off = 1; off < 256; off <<= 1) {
        int u = (t >= off) ? sm[t - off] : 0;
        __syncthreads();
        sm[t] += u;
        __syncthreads();
    }
    if (t < NBUCK) bbase[t] = sm[t] - v;   // exclusive
    if (t == 0) { bbase[NBUCK] = N_EDGES; offs[N_NODES] = N_EDGES; }
}

// ---- pass B: per-bucket count/scan/fill -> csr, offs, dis ------------------
__global__ __launch_bounds__(256) void k_csr(const unsigned* __restrict__ ebuf,
                                             const int* __restrict__ gcnt,
                                             const int* __restrict__ bbase,
                                             int* __restrict__ offs,
                                             float* __restrict__ dis,
                                             int* __restrict__ csr) {
    __shared__ int cntA[256];
    __shared__ int scanA[256];
    int b = blockIdx.x;
    int t = threadIdx.x;
    int n0 = b * 256;
    int count = gcnt[b];
    int base  = bbase[b];
    const unsigned* eb = ebuf + (size_t)b * BUCKCAP;

    cntA[t] = 0;
    __syncthreads();
    for (int i = t; i < count; i += 256)
        atomicAdd(&cntA[eb[i] >> 16 & 0xFF], 1);
    // note: (v>>16) - n0 == (v>>16)&0xFF since bucket = dst>>8
    __syncthreads();
    int c = cntA[t];
    scanA[t] = c;
    __syncthreads();
    for (int off = 1; off < 256; off <<= 1) {
        int u = (t >= off) ? scanA[t - off] : 0;
        __syncthreads();
        scanA[t] += u;
        __syncthreads();
    }
    int excl = scanA[t] - c;
    int n = n0 + t;
    if (n < N_NODES) {
        offs[n] = base + excl;
        dis[n]  = rsqrtf((float)c + 1.0f);
    }
    scanA[t] = excl;      // keep exclusive prefix for pass 2
    cntA[t] = 0;          // becomes fill counter
    __syncthreads();
    for (int i = t; i < count; i += 256) {
        unsigned v = eb[i];
        int ln = (v >> 16) & 0xFF;
        int p = atomicAdd(&cntA[ln], 1);
        csr[base + scanA[ln] + p] = (int)(v & 0xFFFFu);
    }
}

// ---- split fp32 -> (bf16 hi, bf16 lo) -------------------------------------
__global__ void k_split(const float* __restrict__ in, short* __restrict__ hi,
                        short* __restrict__ lo, int n4) {
    int i = blockIdx.x * blockDim.x + threadIdx.x;
    if (i >= n4) return;
    float4 v = ((const float4*)in)[i];
    unsigned short h0 = f2bf(v.x), h1 = f2bf(v.y), h2 = f2bf(v.z), h3 = f2bf(v.w);
    unsigned short l0 = f2bf(v.x - bf2f(h0)), l1 = f2bf(v.y - bf2f(h1));
    unsigned short l2 = f2bf(v.z - bf2f(h2)), l3 = f2bf(v.w - bf2f(h3));
    ushort4 vh; vh.x = h0; vh.y = h1; vh.z = h2; vh.w = h3;
    ushort4 vl; vl.x = l0; vl.y = l1; vl.z = l2; vl.w = l3;
    ((ushort4*)hi)[i] = vh;
    ((ushort4*)lo)[i] = vl;
}

// ---- all three W[128k x 128n] -> W^T splits [3][128n][128k] hi/lo ----------
__global__ void k_wsplit3(const float* __restrict__ W0, const float* __restrict__ W1,
                          const float* __restrict__ W2, short* __restrict__ Wth,
                          short* __restrict__ Wtl) {
    int which = blockIdx.y;
    const float* W = which == 0 ? W0 : (which == 1 ? W1 : W2);
    int tid = blockIdx.x * blockDim.x + threadIdx.x;   // 16384
    int k = tid & 127, n = tid >> 7;
    float w = W[k * HID + n];
    unsigned short h = f2bf(w);
    Wth[which * HID * HID + n * HID + k] = (short)h;
    Wtl[which * HID * HID + n * HID + k] = (short)f2bf(w - bf2f(h));
}

// ---- MFMA GEMM: (A @ W) * scale[row] -> bf16 hi/lo pair --------------------
__global__ __launch_bounds__(256) void k_gemm_mfma(const short* __restrict__ Ah,
                                                   const short* __restrict__ Al,
                                                   const short* __restrict__ Wh,
                                                   const short* __restrict__ Wl,
                                                   unsigned short* __restrict__ th,
                                                   unsigned short* __restrict__ tl,
                                                   int M,
                                                   const float* __restrict__ scale) {
    int wid  = threadIdx.x >> 6;
    int lane = threadIdx.x & 63;
    int row0 = blockIdx.x * 64 + wid * 16;
    int r    = lane & 15;
    int ko   = (lane >> 4) * 8;

    const short* Arh = Ah + (size_t)(row0 + r) * HID;
    const short* Arl = Al + (size_t)(row0 + r) * HID;
    short8 afh[4], afl[4];
    #pragma unroll
    for (int c = 0; c < 4; c++) {
        afh[c] = *(const short8*)(Arh + c * 32 + ko);
        afl[c] = *(const short8*)(Arl + c * 32 + ko);
    }

    f32x4 acc[8];
    #pragma unroll
    for (int n = 0; n < 8; n++) acc[n] = (f32x4){0.f, 0.f, 0.f, 0.f};

    #pragma unroll
    for (int n = 0; n < 8; n++) {
        const short* Wrh = Wh + (size_t)(n * 16 + r) * HID;
        const short* Wrl = Wl + (size_t)(n * 16 + r) * HID;
        #pragma unroll
        for (int c = 0; c < 4; c++) {
            short8 bh = *(const short8*)(Wrh + c * 32 + ko);
            short8 bl = *(const short8*)(Wrl + c * 32 + ko);
            acc[n] = __builtin_amdgcn_mfma_f32_16x16x32_bf16(afh[c], bh, acc[n], 0, 0, 0);
            acc[n] = __builtin_amdgcn_mfma_f32_16x16x32_bf16(afl[c], bh, acc[n], 0, 0, 0);
            acc[n] = __builtin_amdgcn_mfma_f32_16x16x32_bf16(afh[c], bl, acc[n], 0, 0, 0);
        }
    }

    int crow = row0 + (lane >> 4) * 4;
    #pragma unroll
    for (int q = 0; q < 4; q++) {
        int gr = crow + q;
        if (gr < M) {
            float s = scale[gr];
            #pragma unroll
            for (int n = 0; n < 8; n++) {
                float v = acc[n][q] * s;
                unsigned short hi = f2bf(v);
                unsigned short lo = f2bf(v - bf2f(hi));
                th[(size_t)gr * HID + n * 16 + (lane & 15)] = hi;
                tl[(size_t)gr * HID + n * 16 + (lane & 15)] = lo;
            }
        }
    }
}

// ---- GCN aggregation: gather bf16-hi rows; self term = hi+lo (exact) -------
__global__ __launch_bounds__(256) void k_agg(const unsigned short* __restrict__ th,
                                             const unsigned short* __restrict__ tl,
                                             const int* __restrict__ offs,
                                             const int* __restrict__ csr_src,
                                             const float* __restrict__ dis,
                                             const float* __restrict__ bias,
                                             float* __restrict__ hout,
                                             short* __restrict__ hh,
                                             short* __restrict__ hl,
                                             int mode) {
    int node = blockIdx.x * 4 + (threadIdx.x >> 6);
    if (node >= N_NODES) return;
    int lane = threadIdx.x & 63;
    int c  = lane & 31;          // col group: cols [c*4, c*4+4)
    int e  = lane >> 5;          // edge slot 0/1
    int beg = offs[node], end = offs[node + 1];
    float dn = dis[node];

    float ax[4] = {}, ay[4] = {}, az[4] = {}, aw[4] = {};
    for (int j = beg; j < end; j += 8) {
        #pragma unroll
        for (int k = 0; k < 4; k++) {
            int jj = j + k * 2 + e;
            int jc = jj < end ? jj : end - 1;
            int s = csr_src[jc];
            float m = (jj < end) ? 1.0f : 0.0f;
            uint2 v = *(const uint2*)&th[(size_t)s * HID + c * 4];
            float v0 = __builtin_bit_cast(float, v.x << 16);
            float v1 = __builtin_bit_cast(float, v.x & 0xFFFF0000u);
            float v2 = __builtin_bit_cast(float, v.y << 16);
            float v3 = __builtin_bit_cast(float, v.y & 0xFFFF0000u);
            ax[k] = fmaf(v0, m, ax[k]);
            ay[k] = fmaf(v1, m, ay[k]);
            az[k] = fmaf(v2, m, az[k]);
            aw[k] = fmaf(v3, m, aw[k]);
        }
    }
    float tx = (ax[0] + ax[1]) + (ax[2] + ax[3]);
    float ty = (ay[0] + ay[1]) + (ay[2] + ay[3]);
    float tz = (az[0] + az[1]) + (az[2] + az[3]);
    float tw = (aw[0] + aw[1]) + (aw[2] + aw[3]);
    tx += __shfl_xor(tx, 32);
    ty += __shfl_xor(ty, 32);
    tz += __shfl_xor(tz, 32);
    tw += __shfl_xor(tw, 32);

    if (e == 0) {
        ushort4 sh = *(const ushort4*)&th[(size_t)node * HID + c * 4];
        ushort4 sl = *(const ushort4*)&tl[(size_t)node * HID + c * 4];
        float4 b4  = *(const float4*)&bias[c * 4];
        float ox = (tx + bf2f(sh.x) + bf2f(sl.x)) * dn + b4.x;
        float oy = (ty + bf2f(sh.y) + bf2f(sl.y)) * dn + b4.y;
        float oz = (tz + bf2f(sh.z) + bf2f(sl.z)) * dn + b4.z;
        float ow = (tw + bf2f(sh.w) + bf2f(sl.w)) * dn + b4.w;
        if (mode == 1) {
            ox = fmaxf(ox, 0.f); oy = fmaxf(oy, 0.f);
            oz = fmaxf(oz, 0.f); ow = fmaxf(ow, 0.f);
            unsigned short hx = f2bf(ox), hy = f2bf(oy), hz = f2bf(oz), hw = f2bf(ow);
            ushort4 vh; vh.x = hx; vh.y = hy; vh.z = hz; vh.w = hw;
            ushort4 vl;
            vl.x = f2bf(ox - bf2f(hx)); vl.y = f2bf(oy - bf2f(hy));
            vl.z = f2bf(oz - bf2f(hz)); vl.w = f2bf(ow - bf2f(hw));
            *(ushort4*)&hh[(size_t)node * HID + c * 4] = vh;
            *(ushort4*)&hl[(size_t)node * HID + c * 4] = vl;
        } else {
            float4 o = make_float4(ox, oy, oz, ow);
            *(float4*)&hout[(size_t)node * HID + c * 4] = o;
        }
    }
}

// ---- graph boundaries from sorted batch ------------------------------------
__global__ void k_bounds(const int* __restrict__ batch, int* __restrict__ gstart) {
    int n = blockIdx.x * blockDim.x + threadIdx.x;
    if (n >= N_NODES) return;
    int b  = batch[n];
    int bp = (n == 0) ? -1 : batch[n - 1];
    for (int g = bp + 1; g <= b; g++) gstart[g] = n;
    if (n == N_NODES - 1)
        for (int g = b + 1; g <= NUM_GRAPHS; g++) gstart[g] = N_NODES;
}

// ---- generalized-mean pool: one block (256t) per graph ----------------------
__global__ __launch_bounds__(256) void k_pool(const float* __restrict__ h,
                                              const int* __restrict__ gstart,
                                              float* __restrict__ pooled) {
    __shared__ float smx[4][64], smy[4][64];
    int g = blockIdx.x;
    int t = threadIdx.x;
    int c = t & 63;          // col group (2 floats)
    int slot = t >> 6;       // 0..3
    int beg = gstart[g], end = gstart[g + 1];

    float sx = 0.f, sy = 0.f;
    for (int n = beg + slot; n < end; n += 4) {
        float2 v = *(const float2*)&h[(size_t)n * HID + c * 2];
        sx += signpow(v.x, false);
        sy += signpow(v.y, false);
    }
    smx[slot][c] = sx; smy[slot][c] = sy;
    __syncthreads();
    if (slot == 0) {
        sx = (smx[0][c] + smx[1][c]) + (smx[2][c] + smx[3][c]);
        sy = (smy[0][c] + smy[1][c]) + (smy[2][c] + smy[3][c]);
        float cnt = fmaxf((float)(end - beg), 1.0f);
        float px = sx / cnt, py = sy / cnt;
        pooled[g * HID + c * 2]     = fmaxf(signpow(px, true), 0.f);
        pooled[g * HID + c * 2 + 1] = fmaxf(signpow(py, true), 0.f);
    }
}

// ---- FF head ---------------------------------------------------------------
__global__ __launch_bounds__(128) void k_ff(const float* __restrict__ pooled,
                                            const float* __restrict__ Wf0,
                                            const float* __restrict__ bf0,
                                            const float* __restrict__ Wf1,
                                            const float* __restrict__ bf1,
                                            float* __restrict__ out) {
    __shared__ float row[128];
    __shared__ float zrow[128];
    int g = blockIdx.x, t = threadIdx.x;
    row[t] = pooled[g * HID + t];
    __syncthreads();
    float acc = bf0[t];
    #pragma unroll 8
    for (int k = 0; k < 128; k++) acc = fmaf(row[k], Wf0[k * 128 + t], acc);
    zrow[t] = fmaxf(acc, 0.f);
    __syncthreads();
    if (t < OUT_DIM) {
        float a2 = bf1[t];
        #pragma unroll 8
        for (int k = 0; k < 128; k++) a2 = fmaf(zrow[k], Wf1[k * OUT_DIM + t], a2);
        out[g * OUT_DIM + t] = a2;
    }
}

// ---------------------------------------------------------------------------
static inline size_t align256(size_t x) { return (x + 255) & ~(size_t)255; }

extern "C" void kernel_launch(void* const* d_in, const int* in_sizes, int n_in,
                              void* d_out, int out_size, void* d_ws, size_t ws_size,
                              hipStream_t stream) {
    const float* x     = (const float*)d_in[0];
    const int*   ei    = (const int*)d_in[1];
    const int*   batch = (const int*)d_in[2];
    const float* W0  = (const float*)d_in[3];  const float* b0  = (const float*)d_in[4];
    const float* W1  = (const float*)d_in[5];  const float* b1  = (const float*)d_in[6];
    const float* W2  = (const float*)d_in[7];  const float* b2  = (const float*)d_in[8];
    const float* Wf0 = (const float*)d_in[9];  const float* bf0 = (const float*)d_in[10];
    const float* Wf1 = (const float*)d_in[11]; const float* bf1 = (const float*)d_in[12];
    float* out = (float*)d_out;

    char* p = (char*)d_ws;
    unsigned short* th = (unsigned short*)p; p += align256((size_t)M_PAD * HID * 2);
    unsigned short* tl = (unsigned short*)p; p += align256((size_t)M_PAD * HID * 2);
    short* bufAh = (short*)p; p += align256((size_t)M_PAD * HID * 2);
    short* bufAl = (short*)p; p += align256((size_t)M_PAD * HID * 2);
    short* bufBh = (short*)p; p += align256((size_t)M_PAD * HID * 2);
    short* bufBl = (short*)p; p += align256((size_t)M_PAD * HID * 2);
    float* h     = (float*)bufBh;   // aliases bufBh+bufBl (contiguous), live only after layer2
    unsigned* ebuf = (unsigned*)p; p += align256((size_t)NBUCK * BUCKCAP * 4);
    int*   gcnt    = (int*)p;   p += align256((size_t)NBUCK * 4);
    int*   bbase   = (int*)p;   p += align256((size_t)(NBUCK + 1) * 4);
    int*   offs    = (int*)p;   p += align256((size_t)(N_NODES + 1) * 4);
    int*   csr     = (int*)p;   p += align256((size_t)N_EDGES * 4);
    float* dis     = (float*)p; p += align256((size_t)N_NODES * 4);
    int*   gstart  = (int*)p;   p += align256((size_t)(NUM_GRAPHS + 1) * 4);
    float* pooled  = (float*)p; p += align256((size_t)NUM_GRAPHS * HID * 4);
    short* Wth     = (short*)p; p += align256((size_t)3 * HID * HID * 2);
    short* Wtl     = (short*)p; p += align256((size_t)3 * HID * HID * 2);

    hipMemsetAsync(gcnt, 0, (size_t)NBUCK * 4, stream);

    const int TB = 256;
    k_bucketize<<<ABLOCKS, 256, 0, stream>>>(ei, gcnt, ebuf);
    k_bscan    <<<1, 256, 0, stream>>>(gcnt, bbase, offs);
    k_csr      <<<NBUCK, 256, 0, stream>>>(ebuf, gcnt, bbase, offs, dis, csr);

    // splits
    int n4 = N_NODES * HID / 4;
    k_split<<<(n4 + TB - 1) / TB, TB, 0, stream>>>(x, bufAh, bufAl, n4);
    dim3 wg(64, 3);
    k_wsplit3<<<wg, 256, 0, stream>>>(W0, W1, W2, Wth, Wtl);

    int gemm_blocks = M_PAD / 64;             // 782
    int agg_blocks  = (N_NODES + 3) / 4;

    // layer 0
    k_gemm_mfma<<<gemm_blocks, 256, 0, stream>>>(bufAh, bufAl, Wth, Wtl,
                                                 th, tl, N_NODES, dis);
    k_agg<<<agg_blocks, 256, 0, stream>>>(th, tl, offs, csr, dis, b0,
                                          nullptr, bufBh, bufBl, 1);
    // layer 1
    k_gemm_mfma<<<gemm_blocks, 256, 0, stream>>>(bufBh, bufBl, Wth + HID * HID, Wtl + HID * HID,
                                                 th, tl, N_NODES, dis);
    k_agg<<<agg_blocks, 256, 0, stream>>>(th, tl, offs, csr, dis, b1,
                                          nullptr, bufAh, bufAl, 1);
    // layer 2 (no relu, fp32 out for pooling)
    k_gemm_mfma<<<gemm_blocks, 256, 0, stream>>>(bufAh, bufAl, Wth + 2 * HID * HID, Wtl + 2 * HID * HID,
                                                 th, tl, N_NODES, dis);
    k_agg<<<agg_blocks, 256, 0, stream>>>(th, tl, offs, csr, dis, b2,
                                          h, nullptr, nullptr, 0);

    k_bounds<<<(N_NODES + TB - 1) / TB, TB, 0, stream>>>(batch, gstart);
    k_pool<<<NUM_GRAPHS, 256, 0, stream>>>(h, gstart, pooled);
    k_ff<<<NUM_GRAPHS, 128, 0, stream>>>(pooled, Wf0, bf0, Wf1, bf1, out);
}

// Round 11
// 249.803 us; speedup vs baseline: 1.3999x; 1.1608x over previous
//
#include <hip/hip_runtime.h>

#define N_NODES   50000
#define M_PAD     50048            // 1564 * 32
#define N_TILES   1564
#define GEMM_GRID 391              // 1564 / 4
#define N_EDGES   800000
#define HID       128
#define OUT_DIM   64
#define NUM_GRAPHS 512
#define EPS       1e-6f
#define NBUCK     196              // buckets of 256 nodes: ceil(50000/256)
#define BUCKCAP   6144             // >> max bucket load (~4400)
#define ABLOCKS   98               // pass-A blocks, 8192 edges each

typedef __attribute__((ext_vector_type(8))) short short8;
typedef __attribute__((ext_vector_type(4))) float f32x4;
typedef __attribute__((ext_vector_type(16))) float f32x16;

static __device__ __forceinline__ unsigned short f2bf(float f) {
    unsigned u = __builtin_bit_cast(unsigned, f);
    u += 0x7FFFu + ((u >> 16) & 1u);           // round-to-nearest-even
    return (unsigned short)(u >> 16);
}
static __device__ __forceinline__ float bf2f(unsigned short h) {
    unsigned u = ((unsigned)h) << 16;
    return __builtin_bit_cast(float, u);
}

static __device__ __forceinline__ float signpow(float x, bool sqrt_mode) {
    if (x == 0.0f) return 0.0f;
    float a = fabsf(x) + EPS;
    float v = sqrt_mode ? sqrtf(a) : a * a;
    return x > 0.0f ? v : -v;
}

// ---- CSR build, pass A: bucket edges by dst>>8 -----------------------------
__global__ __launch_bounds__(256) void k_bucketize(const int* __restrict__ ei,
                                                   int* __restrict__ gcnt,
                                                   unsigned* __restrict__ ebuf) {
    __shared__ int lcnt[NBUCK];
    __shared__ int lbase[NBUCK];
    int tid = threadIdx.x;
    for (int i = tid; i < NBUCK; i += 256) lcnt[i] = 0;
    __syncthreads();

    const uint4* src4 = (const uint4*)ei;
    const uint4* dst4 = (const uint4*)(ei + N_EDGES);
    int base4 = blockIdx.x * 2048;

    #pragma unroll 1
    for (int it = 0; it < 8; it++) {
        int i4 = base4 + it * 256 + tid;
        if (i4 < N_EDGES / 4) {
            uint4 d = dst4[i4];
            atomicAdd(&lcnt[d.x >> 8], 1);
            atomicAdd(&lcnt[d.y >> 8], 1);
            atomicAdd(&lcnt[d.z >> 8], 1);
            atomicAdd(&lcnt[d.w >> 8], 1);
        }
    }
    __syncthreads();
    for (int i = tid; i < NBUCK; i += 256) {
        lbase[i] = atomicAdd(&gcnt[i], lcnt[i]);
        lcnt[i] = 0;
    }
    __syncthreads();

    #pragma unroll 1
    for (int it = 0; it < 8; it++) {
        int i4 = base4 + it * 256 + tid;
        if (i4 < N_EDGES / 4) {
            uint4 d = dst4[i4];
            uint4 s = src4[i4];
            unsigned dd[4] = {d.x, d.y, d.z, d.w};
            unsigned ss[4] = {s.x, s.y, s.z, s.w};
            #pragma unroll
            for (int k = 0; k < 4; k++) {
                int b = dd[k] >> 8;
                int p = atomicAdd(&lcnt[b], 1);
                ebuf[(size_t)b * BUCKCAP + lbase[b] + p] = ss[k] | (dd[k] << 16);
            }
        }
    }
}

__global__ __launch_bounds__(256) void k_bscan(const int* __restrict__ gcnt,
                                               int* __restrict__ bbase,
                                               int* __restrict__ offs) {
    __shared__ int sm[256];
    int t = threadIdx.x;
    int v = (t < NBUCK) ? gcnt[t] : 0;
    sm[t] = v;
    __syncthreads();
    for (int off = 1; off < 256; off <<= 1) {
        int u = (t >= off) ? sm[t - off] : 0;
        __syncthreads();
        sm[t] += u;
        __syncthreads();
    }
    if (t < NBUCK) bbase[t] = sm[t] - v;   // exclusive
    if (t == 0) { bbase[NBUCK] = N_EDGES; offs[N_NODES] = N_EDGES; }
}

__global__ __launch_bounds__(256) void k_csr(const unsigned* __restrict__ ebuf,
                                             const int* __restrict__ gcnt,
                                             const int* __restrict__ bbase,
                                             int* __restrict__ offs,
                                             float* __restrict__ dis,
                                             int* __restrict__ csr) {
    __shared__ int cntA[256];
    __shared__ int scanA[256];
    int b = blockIdx.x;
    int t = threadIdx.x;
    int n0 = b * 256;
    int count = gcnt[b];
    int base  = bbase[b];
    const unsigned* eb = ebuf + (size_t)b * BUCKCAP;

    cntA[t] = 0;
    __syncthreads();
    for (int i = t; i < count; i += 256)
        atomicAdd(&cntA[eb[i] >> 16 & 0xFF], 1);
    __syncthreads();
    int c = cntA[t];
    scanA[t] = c;
    __syncthreads();
    for (int off = 1; off < 256; off <<= 1) {
        int u = (t >= off) ? scanA[t - off] : 0;
        __syncthreads();
        scanA[t] += u;
        __syncthreads();
    }
    int excl = scanA[t] - c;
    int n = n0 + t;
    if (n < N_NODES) {
        offs[n] = base + excl;
        dis[n]  = rsqrtf((float)c + 1.0f);
    }
    scanA[t] = excl;
    cntA[t] = 0;
    __syncthreads();
    for (int i = t; i < count; i += 256) {
        unsigned v = eb[i];
        int ln = (v >> 16) & 0xFF;
        int p = atomicAdd(&cntA[ln], 1);
        csr[base + scanA[ln] + p] = (int)(v & 0xFFFFu);
    }
}

// ---- split fp32 -> (bf16 hi, bf16 lo) -------------------------------------
__global__ void k_split(const float* __restrict__ in, short* __restrict__ hi,
                        short* __restrict__ lo, int n4) {
    int i = blockIdx.x * blockDim.x + threadIdx.x;
    if (i >= n4) return;
    float4 v = ((const float4*)in)[i];
    unsigned short h0 = f2bf(v.x), h1 = f2bf(v.y), h2 = f2bf(v.z), h3 = f2bf(v.w);
    unsigned short l0 = f2bf(v.x - bf2f(h0)), l1 = f2bf(v.y - bf2f(h1));
    unsigned short l2 = f2bf(v.z - bf2f(h2)), l3 = f2bf(v.w - bf2f(h3));
    ushort4 vh; vh.x = h0; vh.y = h1; vh.z = h2; vh.w = h3;
    ushort4 vl; vl.x = l0; vl.y = l1; vl.z = l2; vl.w = l3;
    ((ushort4*)hi)[i] = vh;
    ((ushort4*)lo)[i] = vl;
}

// ---- all three W[128k x 128n] -> W^T splits [3][128n][128k] hi/lo ----------
__global__ void k_wsplit3(const float* __restrict__ W0, const float* __restrict__ W1,
                          const float* __restrict__ W2, short* __restrict__ Wth,
                          short* __restrict__ Wtl) {
    int which = blockIdx.y;
    const float* W = which == 0 ? W0 : (which == 1 ? W1 : W2);
    int tid = blockIdx.x * blockDim.x + threadIdx.x;   // 16384
    int k = tid & 127, n = tid >> 7;
    float w = W[k * HID + n];
    unsigned short h = f2bf(w);
    Wth[which * HID * HID + n * HID + k] = (short)h;
    Wtl[which * HID * HID + n * HID + k] = (short)f2bf(w - bf2f(h));
}

// ---- MFMA GEMM (32x32x16): W in registers, grid-stride over row tiles ------
// wave w owns cols [w*32, w*32+32); per tile: preload 16 A-frags, 24 MFMA.
__global__ __launch_bounds__(256) void k_gemm_mfma(const short* __restrict__ Ah,
                                                   const short* __restrict__ Al,
                                                   const short* __restrict__ Wh,
                                                   const short* __restrict__ Wl,
                                                   unsigned short* __restrict__ th,
                                                   unsigned short* __restrict__ tl,
                                                   const float* __restrict__ scale) {
    int lane = threadIdx.x & 63;
    int col  = (threadIdx.x >> 6) * 32 + (lane & 31);
    int kh   = lane >> 5;                 // k-half: elements kh*8 .. kh*8+8 of each 16-k step

    // B preload: 8 k-steps, hi+lo  (64 VGPRs)
    short8 bh[8], bl[8];
    #pragma unroll
    for (int ks = 0; ks < 8; ks++) {
        bh[ks] = *(const short8*)(Wh + (size_t)col * HID + ks * 16 + kh * 8);
        bl[ks] = *(const short8*)(Wl + (size_t)col * HID + ks * 16 + kh * 8);
    }

    for (int tile = blockIdx.x; tile < N_TILES; tile += GEMM_GRID) {
        int row0 = tile * 32;
        const short* Ar_h = Ah + (size_t)(row0 + (lane & 31)) * HID + kh * 8;
        const short* Ar_l = Al + (size_t)(row0 + (lane & 31)) * HID + kh * 8;
        short8 ah[8], al[8];
        #pragma unroll
        for (int ks = 0; ks < 8; ks++) {
            ah[ks] = *(const short8*)(Ar_h + ks * 16);
            al[ks] = *(const short8*)(Ar_l + ks * 16);
        }

        f32x16 acc = {0.f};
        #pragma unroll
        for (int ks = 0; ks < 8; ks++) {
            acc = __builtin_amdgcn_mfma_f32_32x32x16_bf16(ah[ks], bh[ks], acc, 0, 0, 0);
            acc = __builtin_amdgcn_mfma_f32_32x32x16_bf16(al[ks], bh[ks], acc, 0, 0, 0);
            acc = __builtin_amdgcn_mfma_f32_32x32x16_bf16(ah[ks], bl[ks], acc, 0, 0, 0);
        }

        #pragma unroll
        for (int reg = 0; reg < 16; reg++) {
            int row = row0 + (reg & 3) + 8 * (reg >> 2) + 4 * kh;
            float v = acc[reg] * scale[row];
            unsigned short hi = f2bf(v);
            th[(size_t)row * HID + col] = hi;
            tl[(size_t)row * HID + col] = f2bf(v - bf2f(hi));
        }
    }
}

// ---- GCN aggregation: gather bf16-hi rows; self term = hi+lo (exact) -------
__global__ __launch_bounds__(256) void k_agg(const unsigned short* __restrict__ th,
                                             const unsigned short* __restrict__ tl,
                                             const int* __restrict__ offs,
                                             const int* __restrict__ csr_src,
                                             const float* __restrict__ dis,
                                             const float* __restrict__ bias,
                                             float* __restrict__ hout,
                                             short* __restrict__ hh,
                                             short* __restrict__ hl,
                                             int mode) {
    int node = blockIdx.x * 4 + (threadIdx.x >> 6);
    if (node >= N_NODES) return;
    int lane = threadIdx.x & 63;
    int c  = lane & 31;          // col group: cols [c*4, c*4+4)
    int e  = lane >> 5;          // edge slot 0/1
    int beg = offs[node], end = offs[node + 1];
    float dn = dis[node];

    float ax[4] = {}, ay[4] = {}, az[4] = {}, aw[4] = {};
    for (int j = beg; j < end; j += 8) {
        #pragma unroll
        for (int k = 0; k < 4; k++) {
            int jj = j + k * 2 + e;
            int jc = jj < end ? jj : end - 1;
            int s = csr_src[jc];
            float m = (jj < end) ? 1.0f : 0.0f;
            uint2 v = *(const uint2*)&th[(size_t)s * HID + c * 4];
            float v0 = __builtin_bit_cast(float, v.x << 16);
            float v1 = __builtin_bit_cast(float, v.x & 0xFFFF0000u);
            float v2 = __builtin_bit_cast(float, v.y << 16);
            float v3 = __builtin_bit_cast(float, v.y & 0xFFFF0000u);
            ax[k] = fmaf(v0, m, ax[k]);
            ay[k] = fmaf(v1, m, ay[k]);
            az[k] = fmaf(v2, m, az[k]);
            aw[k] = fmaf(v3, m, aw[k]);
        }
    }
    float tx = (ax[0] + ax[1]) + (ax[2] + ax[3]);
    float ty = (ay[0] + ay[1]) + (ay[2] + ay[3]);
    float tz = (az[0] + az[1]) + (az[2] + az[3]);
    float tw = (aw[0] + aw[1]) + (aw[2] + aw[3]);
    tx += __shfl_xor(tx, 32);
    ty += __shfl_xor(ty, 32);
    tz += __shfl_xor(tz, 32);
    tw += __shfl_xor(tw, 32);

    if (e == 0) {
        ushort4 sh = *(const ushort4*)&th[(size_t)node * HID + c * 4];
        ushort4 sl = *(const ushort4*)&tl[(size_t)node * HID + c * 4];
        float4 b4  = *(const float4*)&bias[c * 4];
        float ox = (tx + bf2f(sh.x) + bf2f(sl.x)) * dn + b4.x;
        float oy = (ty + bf2f(sh.y) + bf2f(sl.y)) * dn + b4.y;
        float oz = (tz + bf2f(sh.z) + bf2f(sl.z)) * dn + b4.z;
        float ow = (tw + bf2f(sh.w) + bf2f(sl.w)) * dn + b4.w;
        if (mode == 1) {
            ox = fmaxf(ox, 0.f); oy = fmaxf(oy, 0.f);
            oz = fmaxf(oz, 0.f); ow = fmaxf(ow, 0.f);
            unsigned short hx = f2bf(ox), hy = f2bf(oy), hz = f2bf(oz), hw = f2bf(ow);
            ushort4 vh; vh.x = hx; vh.y = hy; vh.z = hz; vh.w = hw;
            ushort4 vl;
            vl.x = f2bf(ox - bf2f(hx)); vl.y = f2bf(oy - bf2f(hy));
            vl.z = f2bf(oz - bf2f(hz)); vl.w = f2bf(ow - bf2f(hw));
            *(ushort4*)&hh[(size_t)node * HID + c * 4] = vh;
            *(ushort4*)&hl[(size_t)node * HID + c * 4] = vl;
        } else {
            float4 o = make_float4(ox, oy, oz, ow);
            *(float4*)&hout[(size_t)node * HID + c * 4] = o;
        }
    }
}

// ---- graph boundaries from sorted batch ------------------------------------
__global__ void k_bounds(const int* __restrict__ batch, int* __restrict__ gstart) {
    int n = blockIdx.x * blockDim.x + threadIdx.x;
    if (n >= N_NODES) return;
    int b  = batch[n];
    int bp = (n == 0) ? -1 : batch[n - 1];
    for (int g = bp + 1; g <= b; g++) gstart[g] = n;
    if (n == N_NODES - 1)
        for (int g = b + 1; g <= NUM_GRAPHS; g++) gstart[g] = N_NODES;
}

// ---- generalized-mean pool: one block (256t) per graph ----------------------
__global__ __launch_bounds__(256) void k_pool(const float* __restrict__ h,
                                              const int* __restrict__ gstart,
                                              float* __restrict__ pooled) {
    __shared__ float smx[4][64], smy[4][64];
    int g = blockIdx.x;
    int t = threadIdx.x;
    int c = t & 63;
    int slot = t >> 6;
    int beg = gstart[g], end = gstart[g + 1];

    float sx = 0.f, sy = 0.f;
    for (int n = beg + slot; n < end; n += 4) {
        float2 v = *(const float2*)&h[(size_t)n * HID + c * 2];
        sx += signpow(v.x, false);
        sy += signpow(v.y, false);
    }
    smx[slot][c] = sx; smy[slot][c] = sy;
    __syncthreads();
    if (slot == 0) {
        sx = (smx[0][c] + smx[1][c]) + (smx[2][c] + smx[3][c]);
        sy = (smy[0][c] + smy[1][c]) + (smy[2][c] + smy[3][c]);
        float cnt = fmaxf((float)(end - beg), 1.0f);
        float px = sx / cnt, py = sy / cnt;
        pooled[g * HID + c * 2]     = fmaxf(signpow(px, true), 0.f);
        pooled[g * HID + c * 2 + 1] = fmaxf(signpow(py, true), 0.f);
    }
}

// ---- FF head ---------------------------------------------------------------
__global__ __launch_bounds__(128) void k_ff(const float* __restrict__ pooled,
                                            const float* __restrict__ Wf0,
                                            const float* __restrict__ bf0,
                                            const float* __restrict__ Wf1,
                                            const float* __restrict__ bf1,
                                            float* __restrict__ out) {
    __shared__ float row[128];
    __shared__ float zrow[128];
    int g = blockIdx.x, t = threadIdx.x;
    row[t] = pooled[g * HID + t];
    __syncthreads();
    float acc = bf0[t];
    #pragma unroll 8
    for (int k = 0; k < 128; k++) acc = fmaf(row[k], Wf0[k * 128 + t], acc);
    zrow[t] = fmaxf(acc, 0.f);
    __syncthreads();
    if (t < OUT_DIM) {
        float a2 = bf1[t];
        #pragma unroll 8
        for (int k = 0; k < 128; k++) a2 = fmaf(zrow[k], Wf1[k * OUT_DIM + t], a2);
        out[g * OUT_DIM + t] = a2;
    }
}

// ---------------------------------------------------------------------------
static inline size_t align256(size_t x) { return (x + 255) & ~(size_t)255; }

extern "C" void kernel_launch(void* const* d_in, const int* in_sizes, int n_in,
                              void* d_out, int out_size, void* d_ws, size_t ws_size,
                              hipStream_t stream) {
    const float* x     = (const float*)d_in[0];
    const int*   ei    = (const int*)d_in[1];
    const int*   batch = (const int*)d_in[2];
    const float* W0  = (const float*)d_in[3];  const float* b0  = (const float*)d_in[4];
    const float* W1  = (const float*)d_in[5];  const float* b1  = (const float*)d_in[6];
    const float* W2  = (const float*)d_in[7];  const float* b2  = (const float*)d_in[8];
    const float* Wf0 = (const float*)d_in[9];  const float* bf0 = (const float*)d_in[10];
    const float* Wf1 = (const float*)d_in[11]; const float* bf1 = (const float*)d_in[12];
    float* out = (float*)d_out;

    char* p = (char*)d_ws;
    unsigned short* th = (unsigned short*)p; p += align256((size_t)M_PAD * HID * 2);
    unsigned short* tl = (unsigned short*)p; p += align256((size_t)M_PAD * HID * 2);
    short* bufAh = (short*)p; p += align256((size_t)M_PAD * HID * 2);
    short* bufAl = (short*)p; p += align256((size_t)M_PAD * HID * 2);
    short* bufBh = (short*)p; p += align256((size_t)M_PAD * HID * 2);
    short* bufBl = (short*)p; p += align256((size_t)M_PAD * HID * 2);
    float* h     = (float*)bufBh;   // aliases bufBh+bufBl (contiguous), live only after layer2
    unsigned* ebuf = (unsigned*)p; p += align256((size_t)NBUCK * BUCKCAP * 4);
    int*   gcnt    = (int*)p;   p += align256((size_t)NBUCK * 4);
    int*   bbase   = (int*)p;   p += align256((size_t)(NBUCK + 1) * 4);
    int*   offs    = (int*)p;   p += align256((size_t)(N_NODES + 1) * 4);
    int*   csr     = (int*)p;   p += align256((size_t)N_EDGES * 4);
    float* dis     = (float*)p; p += align256((size_t)N_NODES * 4);
    int*   gstart  = (int*)p;   p += align256((size_t)(NUM_GRAPHS + 1) * 4);
    float* pooled  = (float*)p; p += align256((size_t)NUM_GRAPHS * HID * 4);
    short* Wth     = (short*)p; p += align256((size_t)3 * HID * HID * 2);
    short* Wtl     = (short*)p; p += align256((size_t)3 * HID * HID * 2);

    hipMemsetAsync(gcnt, 0, (size_t)NBUCK * 4, stream);

    const int TB = 256;
    k_bucketize<<<ABLOCKS, 256, 0, stream>>>(ei, gcnt, ebuf);
    k_bscan    <<<1, 256, 0, stream>>>(gcnt, bbase, offs);
    k_csr      <<<NBUCK, 256, 0, stream>>>(ebuf, gcnt, bbase, offs, dis, csr);

    // splits
    int n4 = N_NODES * HID / 4;
    k_split<<<(n4 + TB - 1) / TB, TB, 0, stream>>>(x, bufAh, bufAl, n4);
    dim3 wg(64, 3);
    k_wsplit3<<<wg, 256, 0, stream>>>(W0, W1, W2, Wth, Wtl);

    int agg_blocks = (N_NODES + 3) / 4;

    // layer 0
    k_gemm_mfma<<<GEMM_GRID, 256, 0, stream>>>(bufAh, bufAl, Wth, Wtl, th, tl, dis);
    k_agg<<<agg_blocks, 256, 0, stream>>>(th, tl, offs, csr, dis, b0,
                                          nullptr, bufBh, bufBl, 1);
    // layer 1
    k_gemm_mfma<<<GEMM_GRID, 256, 0, stream>>>(bufBh, bufBl, Wth + HID * HID, Wtl + HID * HID,
                                               th, tl, dis);
    k_agg<<<agg_blocks, 256, 0, stream>>>(th, tl, offs, csr, dis, b1,
                                          nullptr, bufAh, bufAl, 1);
    // layer 2 (no relu, fp32 out for pooling)
    k_gemm_mfma<<<GEMM_GRID, 256, 0, stream>>>(bufAh, bufAl, Wth + 2 * HID * HID, Wtl + 2 * HID * HID,
                                               th, tl, dis);
    k_agg<<<agg_blocks, 256, 0, stream>>>(th, tl, offs, csr, dis, b2,
                                          h, nullptr, nullptr, 0);

    k_bounds<<<(N_NODES + TB - 1) / TB, TB, 0, stream>>>(batch, gstart);
    k_pool<<<NUM_GRAPHS, 256, 0, stream>>>(h, gstart, pooled);
    k_ff<<<NUM_GRAPHS, 128, 0, stream>>>(pooled, Wf0, bf0, Wf1, bf1, out);
}

// Round 12
// 227.582 us; speedup vs baseline: 1.5366x; 1.0976x over previous
//
#include <hip/hip_runtime.h>

#define N_NODES   50000
#define M_PAD     50048            // 1564 * 32
#define N_TILES   1564
#define GEMM_GRID 391              // 1564 / 4
#define N_EDGES   800000
#define HID       128
#define OUT_DIM   64
#define NUM_GRAPHS 512
#define EPS       1e-6f
#define NBUCK     196              // buckets of 256 nodes: ceil(50000/256)
#define BUCKCAP   6144             // >> max bucket load (~4400)
#define ABLOCKS   98               // pass-A blocks, 8192 edges each

typedef __attribute__((ext_vector_type(8))) short short8;
typedef __attribute__((ext_vector_type(4))) float f32x4;
typedef __attribute__((ext_vector_type(16))) float f32x16;

static __device__ __forceinline__ unsigned short f2bf(float f) {
    unsigned u = __builtin_bit_cast(unsigned, f);
    u += 0x7FFFu + ((u >> 16) & 1u);           // round-to-nearest-even
    return (unsigned short)(u >> 16);
}
static __device__ __forceinline__ float bf2f(unsigned short h) {
    unsigned u = ((unsigned)h) << 16;
    return __builtin_bit_cast(float, u);
}

static __device__ __forceinline__ float signpow(float x, bool sqrt_mode) {
    if (x == 0.0f) return 0.0f;
    float a = fabsf(x) + EPS;
    float v = sqrt_mode ? sqrtf(a) : a * a;
    return x > 0.0f ? v : -v;
}

// ---- CSR build, pass A: bucket edges by dst>>8 -----------------------------
__global__ __launch_bounds__(256) void k_bucketize(const int* __restrict__ ei,
                                                   int* __restrict__ gcnt,
                                                   unsigned* __restrict__ ebuf) {
    __shared__ int lcnt[NBUCK];
    __shared__ int lbase[NBUCK];
    int tid = threadIdx.x;
    for (int i = tid; i < NBUCK; i += 256) lcnt[i] = 0;
    __syncthreads();

    const uint4* src4 = (const uint4*)ei;
    const uint4* dst4 = (const uint4*)(ei + N_EDGES);
    int base4 = blockIdx.x * 2048;

    #pragma unroll 1
    for (int it = 0; it < 8; it++) {
        int i4 = base4 + it * 256 + tid;
        if (i4 < N_EDGES / 4) {
            uint4 d = dst4[i4];
            atomicAdd(&lcnt[d.x >> 8], 1);
            atomicAdd(&lcnt[d.y >> 8], 1);
            atomicAdd(&lcnt[d.z >> 8], 1);
            atomicAdd(&lcnt[d.w >> 8], 1);
        }
    }
    __syncthreads();
    for (int i = tid; i < NBUCK; i += 256) {
        lbase[i] = atomicAdd(&gcnt[i], lcnt[i]);
        lcnt[i] = 0;
    }
    __syncthreads();

    #pragma unroll 1
    for (int it = 0; it < 8; it++) {
        int i4 = base4 + it * 256 + tid;
        if (i4 < N_EDGES / 4) {
            uint4 d = dst4[i4];
            uint4 s = src4[i4];
            unsigned dd[4] = {d.x, d.y, d.z, d.w};
            unsigned ss[4] = {s.x, s.y, s.z, s.w};
            #pragma unroll
            for (int k = 0; k < 4; k++) {
                int b = dd[k] >> 8;
                int p = atomicAdd(&lcnt[b], 1);
                ebuf[(size_t)b * BUCKCAP + lbase[b] + p] = ss[k] | (dd[k] << 16);
            }
        }
    }
}

__global__ __launch_bounds__(256) void k_bscan(const int* __restrict__ gcnt,
                                               int* __restrict__ bbase,
                                               int* __restrict__ offs) {
    __shared__ int sm[256];
    int t = threadIdx.x;
    int v = (t < NBUCK) ? gcnt[t] : 0;
    sm[t] = v;
    __syncthreads();
    for (int off = 1; off < 256; off <<= 1) {
        int u = (t >= off) ? sm[t - off] : 0;
        __syncthreads();
        sm[t] += u;
        __syncthreads();
    }
    if (t < NBUCK) bbase[t] = sm[t] - v;   // exclusive
    if (t == 0) { bbase[NBUCK] = N_EDGES; offs[N_NODES] = N_EDGES; }
}

__global__ __launch_bounds__(256) void k_csr(const unsigned* __restrict__ ebuf,
                                             const int* __restrict__ gcnt,
                                             const int* __restrict__ bbase,
                                             int* __restrict__ offs,
                                             float* __restrict__ dis,
                                             int* __restrict__ csr) {
    __shared__ int cntA[256];
    __shared__ int scanA[256];
    int b = blockIdx.x;
    int t = threadIdx.x;
    int n0 = b * 256;
    int count = gcnt[b];
    int base  = bbase[b];
    const unsigned* eb = ebuf + (size_t)b * BUCKCAP;

    cntA[t] = 0;
    __syncthreads();
    for (int i = t; i < count; i += 256)
        atomicAdd(&cntA[eb[i] >> 16 & 0xFF], 1);
    __syncthreads();
    int c = cntA[t];
    scanA[t] = c;
    __syncthreads();
    for (int off = 1; off < 256; off <<= 1) {
        int u = (t >= off) ? scanA[t - off] : 0;
        __syncthreads();
        scanA[t] += u;
        __syncthreads();
    }
    int excl = scanA[t] - c;
    int n = n0 + t;
    if (n < N_NODES) {
        offs[n] = base + excl;
        dis[n]  = rsqrtf((float)c + 1.0f);
    }
    scanA[t] = excl;
    cntA[t] = 0;
    __syncthreads();
    for (int i = t; i < count; i += 256) {
        unsigned v = eb[i];
        int ln = (v >> 16) & 0xFF;
        int p = atomicAdd(&cntA[ln], 1);
        csr[base + scanA[ln] + p] = (int)(v & 0xFFFFu);
    }
}

// ---- split fp32 -> (bf16 hi, bf16 lo) -------------------------------------
__global__ void k_split(const float* __restrict__ in, short* __restrict__ hi,
                        short* __restrict__ lo, int n4) {
    int i = blockIdx.x * blockDim.x + threadIdx.x;
    if (i >= n4) return;
    float4 v = ((const float4*)in)[i];
    unsigned short h0 = f2bf(v.x), h1 = f2bf(v.y), h2 = f2bf(v.z), h3 = f2bf(v.w);
    unsigned short l0 = f2bf(v.x - bf2f(h0)), l1 = f2bf(v.y - bf2f(h1));
    unsigned short l2 = f2bf(v.z - bf2f(h2)), l3 = f2bf(v.w - bf2f(h3));
    ushort4 vh; vh.x = h0; vh.y = h1; vh.z = h2; vh.w = h3;
    ushort4 vl; vl.x = l0; vl.y = l1; vl.z = l2; vl.w = l3;
    ((ushort4*)hi)[i] = vh;
    ((ushort4*)lo)[i] = vl;
}

// ---- all three W[128k x 128n] -> W^T splits [3][128n][128k] hi/lo ----------
__global__ void k_wsplit3(const float* __restrict__ W0, const float* __restrict__ W1,
                          const float* __restrict__ W2, short* __restrict__ Wth,
                          short* __restrict__ Wtl) {
    int which = blockIdx.y;
    const float* W = which == 0 ? W0 : (which == 1 ? W1 : W2);
    int tid = blockIdx.x * blockDim.x + threadIdx.x;   // 16384
    int k = tid & 127, n = tid >> 7;
    float w = W[k * HID + n];
    unsigned short h = f2bf(w);
    Wth[which * HID * HID + n * HID + k] = (short)h;
    Wtl[which * HID * HID + n * HID + k] = (short)f2bf(w - bf2f(h));
}

// ---- MFMA GEMM (32x32x16): W in regs, A tile staged in LDS (XOR-swizzled) --
// Block = 4 waves; wave w owns cols [w*32, w*32+32). Per tile: cooperative
// stage of A (32x128 hi+lo, 16 KB), then each wave ds_reads its fragments.
__global__ __launch_bounds__(256) void k_gemm_mfma(const short* __restrict__ Ah,
                                                   const short* __restrict__ Al,
                                                   const short* __restrict__ Wh,
                                                   const short* __restrict__ Wl,
                                                   unsigned short* __restrict__ th,
                                                   unsigned short* __restrict__ tl,
                                                   const float* __restrict__ scale) {
    __shared__ short As_h[32 * 128];   // 8 KB, col-group XOR-swizzled by row&7
    __shared__ short As_l[32 * 128];   // 8 KB
    int tid  = threadIdx.x;
    int lane = tid & 63;
    int col  = (tid >> 6) * 32 + (lane & 31);
    int kh   = lane >> 5;                 // k-half: elems kh*8.. of each 16-k step
    int r    = lane & 31;

    // B preload: 8 k-steps, hi+lo  (64 VGPRs)
    short8 bh[8], bl[8];
    #pragma unroll
    for (int ks = 0; ks < 8; ks++) {
        bh[ks] = *(const short8*)(Wh + (size_t)col * HID + ks * 16 + kh * 8);
        bl[ks] = *(const short8*)(Wl + (size_t)col * HID + ks * 16 + kh * 8);
    }

    // staging indices: unit u covers row=u>>4, colgroup cg=u&15 (short8 units)
    int su0 = tid, su1 = tid + 256;
    int sr0 = su0 >> 4, sc0 = su0 & 15;
    int sr1 = su1 >> 4, sc1 = su1 & 15;
    int sw0 = sr0 * 128 + ((sc0 ^ (sr0 & 7)) * 8);
    int sw1 = sr1 * 128 + ((sc1 ^ (sr1 & 7)) * 8);

    for (int tile = blockIdx.x; tile < N_TILES; tile += GEMM_GRID) {
        int row0 = tile * 32;
        __syncthreads();   // previous tile's ds_reads complete before overwrite
        {
            const short* gh = Ah + (size_t)row0 * HID;
            const short* gl = Al + (size_t)row0 * HID;
            *(short8*)&As_h[sw0] = *(const short8*)(gh + sr0 * HID + sc0 * 8);
            *(short8*)&As_h[sw1] = *(const short8*)(gh + sr1 * HID + sc1 * 8);
            *(short8*)&As_l[sw0] = *(const short8*)(gl + sr0 * HID + sc0 * 8);
            *(short8*)&As_l[sw1] = *(const short8*)(gl + sr1 * HID + sc1 * 8);
        }
        __syncthreads();

        short8 ah[8], al[8];
        #pragma unroll
        for (int ks = 0; ks < 8; ks++) {
            int cg = ks * 2 + kh;
            int off = r * 128 + ((cg ^ (r & 7)) * 8);
            ah[ks] = *(const short8*)&As_h[off];
            al[ks] = *(const short8*)&As_l[off];
        }

        f32x16 acc = {0.f};
        #pragma unroll
        for (int ks = 0; ks < 8; ks++) {
            acc = __builtin_amdgcn_mfma_f32_32x32x16_bf16(ah[ks], bh[ks], acc, 0, 0, 0);
            acc = __builtin_amdgcn_mfma_f32_32x32x16_bf16(al[ks], bh[ks], acc, 0, 0, 0);
            acc = __builtin_amdgcn_mfma_f32_32x32x16_bf16(ah[ks], bl[ks], acc, 0, 0, 0);
        }

        #pragma unroll
        for (int reg = 0; reg < 16; reg++) {
            int row = row0 + (reg & 3) + 8 * (reg >> 2) + 4 * kh;
            float v = acc[reg] * scale[row];
            unsigned short hi = f2bf(v);
            th[(size_t)row * HID + col] = hi;
            tl[(size_t)row * HID + col] = f2bf(v - bf2f(hi));
        }
    }
}

// ---- GCN aggregation: gather bf16-hi rows; self term = hi+lo (exact) -------
__global__ __launch_bounds__(256) void k_agg(const unsigned short* __restrict__ th,
                                             const unsigned short* __restrict__ tl,
                                             const int* __restrict__ offs,
                                             const int* __restrict__ csr_src,
                                             const float* __restrict__ dis,
                                             const float* __restrict__ bias,
                                             float* __restrict__ hout,
                                             short* __restrict__ hh,
                                             short* __restrict__ hl,
                                             int mode) {
    int node = blockIdx.x * 4 + (threadIdx.x >> 6);
    if (node >= N_NODES) return;
    int lane = threadIdx.x & 63;
    int c  = lane & 31;          // col group: cols [c*4, c*4+4)
    int e  = lane >> 5;          // edge slot 0/1
    int beg = offs[node], end = offs[node + 1];
    float dn = dis[node];

    float ax[4] = {}, ay[4] = {}, az[4] = {}, aw[4] = {};
    for (int j = beg; j < end; j += 8) {
        #pragma unroll
        for (int k = 0; k < 4; k++) {
            int jj = j + k * 2 + e;
            int jc = jj < end ? jj : end - 1;
            int s = csr_src[jc];
            float m = (jj < end) ? 1.0f : 0.0f;
            uint2 v = *(const uint2*)&th[(size_t)s * HID + c * 4];
            float v0 = __builtin_bit_cast(float, v.x << 16);
            float v1 = __builtin_bit_cast(float, v.x & 0xFFFF0000u);
            float v2 = __builtin_bit_cast(float, v.y << 16);
            float v3 = __builtin_bit_cast(float, v.y & 0xFFFF0000u);
            ax[k] = fmaf(v0, m, ax[k]);
            ay[k] = fmaf(v1, m, ay[k]);
            az[k] = fmaf(v2, m, az[k]);
            aw[k] = fmaf(v3, m, aw[k]);
        }
    }
    float tx = (ax[0] + ax[1]) + (ax[2] + ax[3]);
    float ty = (ay[0] + ay[1]) + (ay[2] + ay[3]);
    float tz = (az[0] + az[1]) + (az[2] + az[3]);
    float tw = (aw[0] + aw[1]) + (aw[2] + aw[3]);
    tx += __shfl_xor(tx, 32);
    ty += __shfl_xor(ty, 32);
    tz += __shfl_xor(tz, 32);
    tw += __shfl_xor(tw, 32);

    if (e == 0) {
        ushort4 sh = *(const ushort4*)&th[(size_t)node * HID + c * 4];
        ushort4 sl = *(const ushort4*)&tl[(size_t)node * HID + c * 4];
        float4 b4  = *(const float4*)&bias[c * 4];
        float ox = (tx + bf2f(sh.x) + bf2f(sl.x)) * dn + b4.x;
        float oy = (ty + bf2f(sh.y) + bf2f(sl.y)) * dn + b4.y;
        float oz = (tz + bf2f(sh.z) + bf2f(sl.z)) * dn + b4.z;
        float ow = (tw + bf2f(sh.w) + bf2f(sl.w)) * dn + b4.w;
        if (mode == 1) {
            ox = fmaxf(ox, 0.f); oy = fmaxf(oy, 0.f);
            oz = fmaxf(oz, 0.f); ow = fmaxf(ow, 0.f);
            unsigned short hx = f2bf(ox), hy = f2bf(oy), hz = f2bf(oz), hw = f2bf(ow);
            ushort4 vh; vh.x = hx; vh.y = hy; vh.z = hz; vh.w = hw;
            ushort4 vl;
            vl.x = f2bf(ox - bf2f(hx)); vl.y = f2bf(oy - bf2f(hy));
            vl.z = f2bf(oz - bf2f(hz)); vl.w = f2bf(ow - bf2f(hw));
            *(ushort4*)&hh[(size_t)node * HID + c * 4] = vh;
            *(ushort4*)&hl[(size_t)node * HID + c * 4] = vl;
        } else {
            float4 o = make_float4(ox, oy, oz, ow);
            *(float4*)&hout[(size_t)node * HID + c * 4] = o;
        }
    }
}

// ---- graph boundaries from sorted batch ------------------------------------
__global__ void k_bounds(const int* __restrict__ batch, int* __restrict__ gstart) {
    int n = blockIdx.x * blockDim.x + threadIdx.x;
    if (n >= N_NODES) return;
    int b  = batch[n];
    int bp = (n == 0) ? -1 : batch[n - 1];
    for (int g = bp + 1; g <= b; g++) gstart[g] = n;
    if (n == N_NODES - 1)
        for (int g = b + 1; g <= NUM_GRAPHS; g++) gstart[g] = N_NODES;
}

// ---- generalized-mean pool: one block (256t) per graph ----------------------
__global__ __launch_bounds__(256) void k_pool(const float* __restrict__ h,
                                              const int* __restrict__ gstart,
                                              float* __restrict__ pooled) {
    __shared__ float smx[4][64], smy[4][64];
    int g = blockIdx.x;
    int t = threadIdx.x;
    int c = t & 63;
    int slot = t >> 6;
    int beg = gstart[g], end = gstart[g + 1];

    float sx = 0.f, sy = 0.f;
    for (int n = beg + slot; n < end; n += 4) {
        float2 v = *(const float2*)&h[(size_t)n * HID + c * 2];
        sx += signpow(v.x, false);
        sy += signpow(v.y, false);
    }
    smx[slot][c] = sx; smy[slot][c] = sy;
    __syncthreads();
    if (slot == 0) {
        sx = (smx[0][c] + smx[1][c]) + (smx[2][c] + smx[3][c]);
        sy = (smy[0][c] + smy[1][c]) + (smy[2][c] + smy[3][c]);
        float cnt = fmaxf((float)(end - beg), 1.0f);
        float px = sx / cnt, py = sy / cnt;
        pooled[g * HID + c * 2]     = fmaxf(signpow(px, true), 0.f);
        pooled[g * HID + c * 2 + 1] = fmaxf(signpow(py, true), 0.f);
    }
}

// ---- FF head ---------------------------------------------------------------
__global__ __launch_bounds__(128) void k_ff(const float* __restrict__ pooled,
                                            const float* __restrict__ Wf0,
                                            const float* __restrict__ bf0,
                                            const float* __restrict__ Wf1,
                                            const float* __restrict__ bf1,
                                            float* __restrict__ out) {
    __shared__ float row[128];
    __shared__ float zrow[128];
    int g = blockIdx.x, t = threadIdx.x;
    row[t] = pooled[g * HID + t];
    __syncthreads();
    float acc = bf0[t];
    #pragma unroll 8
    for (int k = 0; k < 128; k++) acc = fmaf(row[k], Wf0[k * 128 + t], acc);
    zrow[t] = fmaxf(acc, 0.f);
    __syncthreads();
    if (t < OUT_DIM) {
        float a2 = bf1[t];
        #pragma unroll 8
        for (int k = 0; k < 128; k++) a2 = fmaf(zrow[k], Wf1[k * OUT_DIM + t], a2);
        out[g * OUT_DIM + t] = a2;
    }
}

// ---------------------------------------------------------------------------
static inline size_t align256(size_t x) { return (x + 255) & ~(size_t)255; }

extern "C" void kernel_launch(void* const* d_in, const int* in_sizes, int n_in,
                              void* d_out, int out_size, void* d_ws, size_t ws_size,
                              hipStream_t stream) {
    const float* x     = (const float*)d_in[0];
    const int*   ei    = (const int*)d_in[1];
    const int*   batch = (const int*)d_in[2];
    const float* W0  = (const float*)d_in[3];  const float* b0  = (const float*)d_in[4];
    const float* W1  = (const float*)d_in[5];  const float* b1  = (const float*)d_in[6];
    const float* W2  = (const float*)d_in[7];  const float* b2  = (const float*)d_in[8];
    const float* Wf0 = (const float*)d_in[9];  const float* bf0 = (const float*)d_in[10];
    const float* Wf1 = (const float*)d_in[11]; const float* bf1 = (const float*)d_in[12];
    float* out = (float*)d_out;

    char* p = (char*)d_ws;
    unsigned short* th = (unsigned short*)p; p += align256((size_t)M_PAD * HID * 2);
    unsigned short* tl = (unsigned short*)p; p += align256((size_t)M_PAD * HID * 2);
    short* bufAh = (short*)p; p += align256((size_t)M_PAD * HID * 2);
    short* bufAl = (short*)p; p += align256((size_t)M_PAD * HID * 2);
    short* bufBh = (short*)p; p += align256((size_t)M_PAD * HID * 2);
    short* bufBl = (short*)p; p += align256((size_t)M_PAD * HID * 2);
    float* h     = (float*)bufBh;   // aliases bufBh+bufBl (contiguous), live only after layer2
    unsigned* ebuf = (unsigned*)p; p += align256((size_t)NBUCK * BUCKCAP * 4);
    int*   gcnt    = (int*)p;   p += align256((size_t)NBUCK * 4);
    int*   bbase   = (int*)p;   p += align256((size_t)(NBUCK + 1) * 4);
    int*   offs    = (int*)p;   p += align256((size_t)(N_NODES + 1) * 4);
    int*   csr     = (int*)p;   p += align256((size_t)N_EDGES * 4);
    float* dis     = (float*)p; p += align256((size_t)N_NODES * 4);
    int*   gstart  = (int*)p;   p += align256((size_t)(NUM_GRAPHS + 1) * 4);
    float* pooled  = (float*)p; p += align256((size_t)NUM_GRAPHS * HID * 4);
    short* Wth     = (short*)p; p += align256((size_t)3 * HID * HID * 2);
    short* Wtl     = (short*)p; p += align256((size_t)3 * HID * HID * 2);

    hipMemsetAsync(gcnt, 0, (size_t)NBUCK * 4, stream);

    const int TB = 256;
    k_bucketize<<<ABLOCKS, 256, 0, stream>>>(ei, gcnt, ebuf);
    k_bscan    <<<1, 256, 0, stream>>>(gcnt, bbase, offs);
    k_csr      <<<NBUCK, 256, 0, stream>>>(ebuf, gcnt, bbase, offs, dis, csr);

    // splits
    int n4 = N_NODES * HID / 4;
    k_split<<<(n4 + TB - 1) / TB, TB, 0, stream>>>(x, bufAh, bufAl, n4);
    dim3 wg(64, 3);
    k_wsplit3<<<wg, 256, 0, stream>>>(W0, W1, W2, Wth, Wtl);

    int agg_blocks = (N_NODES + 3) / 4;

    // layer 0
    k_gemm_mfma<<<GEMM_GRID, 256, 0, stream>>>(bufAh, bufAl, Wth, Wtl, th, tl, dis);
    k_agg<<<agg_blocks, 256, 0, stream>>>(th, tl, offs, csr, dis, b0,
                                          nullptr, bufBh, bufBl, 1);
    // layer 1
    k_gemm_mfma<<<GEMM_GRID, 256, 0, stream>>>(bufBh, bufBl, Wth + HID * HID, Wtl + HID * HID,
                                               th, tl, dis);
    k_agg<<<agg_blocks, 256, 0, stream>>>(th, tl, offs, csr, dis, b1,
                                          nullptr, bufAh, bufAl, 1);
    // layer 2 (no relu, fp32 out for pooling)
    k_gemm_mfma<<<GEMM_GRID, 256, 0, stream>>>(bufAh, bufAl, Wth + 2 * HID * HID, Wtl + 2 * HID * HID,
                                               th, tl, dis);
    k_agg<<<agg_blocks, 256, 0, stream>>>(th, tl, offs, csr, dis, b2,
                                          h, nullptr, nullptr, 0);

    k_bounds<<<(N_NODES + TB - 1) / TB, TB, 0, stream>>>(batch, gstart);
    k_pool<<<NUM_GRAPHS, 256, 0, stream>>>(h, gstart, pooled);
    k_ff<<<NUM_GRAPHS, 128, 0, stream>>>(pooled, Wf0, bf0, Wf1, bf1, out);
}

// Round 13
// 206.318 us; speedup vs baseline: 1.6950x; 1.1031x over previous
//
#include <hip/hip_runtime.h>

#define N_NODES   50000
#define M_PAD     50048            // 1564 * 32
#define N_TILES   1564
#define GEMM_GRID 782              // 2 tiles per block
#define N_EDGES   800000
#define HID       128
#define OUT_DIM   64
#define NUM_GRAPHS 512
#define EPS       1e-6f
#define NBUCK     196              // buckets of 256 nodes
#define BUCKCAP   6144
#define ABLOCKS   98

typedef __attribute__((ext_vector_type(8))) short short8;
typedef __attribute__((ext_vector_type(16))) float f32x16;

static __device__ __forceinline__ unsigned short f2bf(float f) {
    unsigned u = __builtin_bit_cast(unsigned, f);
    u += 0x7FFFu + ((u >> 16) & 1u);           // round-to-nearest-even
    return (unsigned short)(u >> 16);
}
static __device__ __forceinline__ float bf2f(unsigned short h) {
    unsigned u = ((unsigned)h) << 16;
    return __builtin_bit_cast(float, u);
}

static __device__ __forceinline__ float signpow(float x, bool sqrt_mode) {
    if (x == 0.0f) return 0.0f;
    float a = fabsf(x) + EPS;
    float v = sqrt_mode ? sqrtf(a) : a * a;
    return x > 0.0f ? v : -v;
}

// ---- CSR build, pass A: bucket edges by dst>>8 -----------------------------
__global__ __launch_bounds__(256) void k_bucketize(const int* __restrict__ ei,
                                                   int* __restrict__ gcnt,
                                                   unsigned* __restrict__ ebuf) {
    __shared__ int lcnt[NBUCK];
    __shared__ int lbase[NBUCK];
    int tid = threadIdx.x;
    for (int i = tid; i < NBUCK; i += 256) lcnt[i] = 0;
    __syncthreads();

    const uint4* src4 = (const uint4*)ei;
    const uint4* dst4 = (const uint4*)(ei + N_EDGES);
    int base4 = blockIdx.x * 2048;

    #pragma unroll 1
    for (int it = 0; it < 8; it++) {
        int i4 = base4 + it * 256 + tid;
        if (i4 < N_EDGES / 4) {
            uint4 d = dst4[i4];
            atomicAdd(&lcnt[d.x >> 8], 1);
            atomicAdd(&lcnt[d.y >> 8], 1);
            atomicAdd(&lcnt[d.z >> 8], 1);
            atomicAdd(&lcnt[d.w >> 8], 1);
        }
    }
    __syncthreads();
    for (int i = tid; i < NBUCK; i += 256) {
        lbase[i] = atomicAdd(&gcnt[i], lcnt[i]);
        lcnt[i] = 0;
    }
    __syncthreads();

    #pragma unroll 1
    for (int it = 0; it < 8; it++) {
        int i4 = base4 + it * 256 + tid;
        if (i4 < N_EDGES / 4) {
            uint4 d = dst4[i4];
            uint4 s = src4[i4];
            unsigned dd[4] = {d.x, d.y, d.z, d.w};
            unsigned ss[4] = {s.x, s.y, s.z, s.w};
            #pragma unroll
            for (int k = 0; k < 4; k++) {
                int b = dd[k] >> 8;
                int p = atomicAdd(&lcnt[b], 1);
                ebuf[(size_t)b * BUCKCAP + lbase[b] + p] = ss[k] | (dd[k] << 16);
            }
        }
    }
}

// ---- pass B: bucket prefix (internal) + per-node count/scan/fill ----------
__global__ __launch_bounds__(256) void k_csr(const unsigned* __restrict__ ebuf,
                                             const int* __restrict__ gcnt,
                                             int* __restrict__ offs,
                                             float* __restrict__ dis,
                                             int* __restrict__ csr) {
    __shared__ int cntA[256];
    __shared__ int scanA[256];
    __shared__ int sbase;
    int b = blockIdx.x;
    int t = threadIdx.x;
    int n0 = b * 256;

    // bucket-level exclusive prefix, computed locally (196 values)
    int v = (t < NBUCK) ? gcnt[t] : 0;
    scanA[t] = v;
    __syncthreads();
    for (int off = 1; off < 256; off <<= 1) {
        int u = (t >= off) ? scanA[t - off] : 0;
        __syncthreads();
        scanA[t] += u;
        __syncthreads();
    }
    if (t == 0) sbase = (b == 0) ? 0 : scanA[b - 1];
    __syncthreads();
    int base  = sbase;
    int count = gcnt[b];
    const unsigned* eb = ebuf + (size_t)b * BUCKCAP;

    cntA[t] = 0;
    __syncthreads();
    for (int i = t; i < count; i += 256)
        atomicAdd(&cntA[eb[i] >> 16 & 0xFF], 1);
    __syncthreads();
    int c = cntA[t];
    scanA[t] = c;
    __syncthreads();
    for (int off = 1; off < 256; off <<= 1) {
        int u = (t >= off) ? scanA[t - off] : 0;
        __syncthreads();
        scanA[t] += u;
        __syncthreads();
    }
    int excl = scanA[t] - c;
    int n = n0 + t;
    if (n < N_NODES) {
        offs[n] = base + excl;
        dis[n]  = rsqrtf((float)c + 1.0f);
    }
    if (b == 0 && t == 0) offs[N_NODES] = N_EDGES;
    scanA[t] = excl;
    cntA[t] = 0;
    __syncthreads();
    for (int i = t; i < count; i += 256) {
        unsigned vv = eb[i];
        int ln = (vv >> 16) & 0xFF;
        int p = atomicAdd(&cntA[ln], 1);
        csr[base + scanA[ln] + p] = (int)(vv & 0xFFFFu);
    }
}

// ---- all three W[128k x 128n] -> W^T splits [3][128n][128k] hi/lo ----------
__global__ void k_wsplit3(const float* __restrict__ W0, const float* __restrict__ W1,
                          const float* __restrict__ W2, short* __restrict__ Wth,
                          short* __restrict__ Wtl) {
    int which = blockIdx.y;
    const float* W = which == 0 ? W0 : (which == 1 ? W1 : W2);
    int tid = blockIdx.x * blockDim.x + threadIdx.x;   // 16384
    int k = tid & 127, n = tid >> 7;
    float w = W[k * HID + n];
    unsigned short h = f2bf(w);
    Wth[which * HID * HID + n * HID + k] = (short)h;
    Wtl[which * HID * HID + n * HID + k] = (short)f2bf(w - bf2f(h));
}

// ---- MFMA GEMM (32x32x16): W in regs, A staged via LDS; th (bf16) out ------
// FP32SRC=1: A is fp32 [N_NODES x 128], hi/lo split computed during staging.
// FP32SRC=0: A given as bf16 hi/lo pair [M_PAD x 128].
template<int FP32SRC>
__global__ __launch_bounds__(256) void k_gemm_mfma(const void* __restrict__ Asrc_h,
                                                   const void* __restrict__ Asrc_l,
                                                   const short* __restrict__ Wh,
                                                   const short* __restrict__ Wl,
                                                   unsigned short* __restrict__ th,
                                                   const float* __restrict__ scale) {
    __shared__ short As_h[32 * 128];   // 8 KB, col-group XOR-swizzled by row&7
    __shared__ short As_l[32 * 128];   // 8 KB
    int tid  = threadIdx.x;
    int lane = tid & 63;
    int col  = (tid >> 6) * 32 + (lane & 31);
    int kh   = lane >> 5;
    int r    = lane & 31;

    // B preload: 8 k-steps, hi+lo  (64 VGPRs)
    short8 bh[8], bl[8];
    #pragma unroll
    for (int ks = 0; ks < 8; ks++) {
        bh[ks] = *(const short8*)(Wh + (size_t)col * HID + ks * 16 + kh * 8);
        bl[ks] = *(const short8*)(Wl + (size_t)col * HID + ks * 16 + kh * 8);
    }

    // staging: unit u = (row u>>4, colgroup u&15) in short8 units
    int su0 = tid, su1 = tid + 256;
    int sr0 = su0 >> 4, sc0 = su0 & 15;
    int sr1 = su1 >> 4, sc1 = su1 & 15;
    int sw0 = sr0 * 128 + ((sc0 ^ (sr0 & 7)) * 8);
    int sw1 = sr1 * 128 + ((sc1 ^ (sr1 & 7)) * 8);

    for (int tile = blockIdx.x; tile < N_TILES; tile += GEMM_GRID) {
        int row0 = tile * 32;
        __syncthreads();
        if (FP32SRC) {
            const float* gx = (const float*)Asrc_h;
            #pragma unroll
            for (int u = 0; u < 2; u++) {
                int sr = u ? sr1 : sr0, sc = u ? sc1 : sc0, sw = u ? sw1 : sw0;
                int gr = row0 + sr; if (gr >= N_NODES) gr = N_NODES - 1;
                const float* src = gx + (size_t)gr * HID + sc * 8;
                float4 a = ((const float4*)src)[0];
                float4 b = ((const float4*)src)[1];
                float vals[8] = {a.x, a.y, a.z, a.w, b.x, b.y, b.z, b.w};
                short8 hi, lo;
                #pragma unroll
                for (int j = 0; j < 8; j++) {
                    unsigned short hh = f2bf(vals[j]);
                    hi[j] = (short)hh;
                    lo[j] = (short)f2bf(vals[j] - bf2f(hh));
                }
                *(short8*)&As_h[sw] = hi;
                *(short8*)&As_l[sw] = lo;
            }
        } else {
            const short* gh = (const short*)Asrc_h + (size_t)row0 * HID;
            const short* gl = (const short*)Asrc_l + (size_t)row0 * HID;
            *(short8*)&As_h[sw0] = *(const short8*)(gh + sr0 * HID + sc0 * 8);
            *(short8*)&As_h[sw1] = *(const short8*)(gh + sr1 * HID + sc1 * 8);
            *(short8*)&As_l[sw0] = *(const short8*)(gl + sr0 * HID + sc0 * 8);
            *(short8*)&As_l[sw1] = *(const short8*)(gl + sr1 * HID + sc1 * 8);
        }
        __syncthreads();

        short8 ah[8], al[8];
        #pragma unroll
        for (int ks = 0; ks < 8; ks++) {
            int cg = ks * 2 + kh;
            int off = r * 128 + ((cg ^ (r & 7)) * 8);
            ah[ks] = *(const short8*)&As_h[off];
            al[ks] = *(const short8*)&As_l[off];
        }

        f32x16 acc = {0.f};
        #pragma unroll
        for (int ks = 0; ks < 8; ks++) {
            acc = __builtin_amdgcn_mfma_f32_32x32x16_bf16(ah[ks], bh[ks], acc, 0, 0, 0);
            acc = __builtin_amdgcn_mfma_f32_32x32x16_bf16(al[ks], bh[ks], acc, 0, 0, 0);
            acc = __builtin_amdgcn_mfma_f32_32x32x16_bf16(ah[ks], bl[ks], acc, 0, 0, 0);
        }

        #pragma unroll
        for (int reg = 0; reg < 16; reg++) {
            int row = row0 + (reg & 3) + 8 * (reg >> 2) + 4 * kh;
            float v = acc[reg] * scale[row];
            th[(size_t)row * HID + col] = f2bf(v);
        }
    }
}

// ---- GCN aggregation: gather bf16 rows; self term bf16-hi ------------------
__global__ __launch_bounds__(256) void k_agg(const unsigned short* __restrict__ th,
                                             const int* __restrict__ offs,
                                             const int* __restrict__ csr_src,
                                             const float* __restrict__ dis,
                                             const float* __restrict__ bias,
                                             float* __restrict__ hout,
                                             short* __restrict__ hh,
                                             short* __restrict__ hl,
                                             int mode) {
    int node = blockIdx.x * 4 + (threadIdx.x >> 6);
    if (node >= N_NODES) return;
    int lane = threadIdx.x & 63;
    int c  = lane & 31;
    int e  = lane >> 5;
    int beg = offs[node], end = offs[node + 1];
    float dn = dis[node];

    float ax[4] = {}, ay[4] = {}, az[4] = {}, aw[4] = {};
    for (int j = beg; j < end; j += 8) {
        #pragma unroll
        for (int k = 0; k < 4; k++) {
            int jj = j + k * 2 + e;
            int jc = jj < end ? jj : end - 1;
            int s = csr_src[jc];
            float m = (jj < end) ? 1.0f : 0.0f;
            uint2 v = *(const uint2*)&th[(size_t)s * HID + c * 4];
            float v0 = __builtin_bit_cast(float, v.x << 16);
            float v1 = __builtin_bit_cast(float, v.x & 0xFFFF0000u);
            float v2 = __builtin_bit_cast(float, v.y << 16);
            float v3 = __builtin_bit_cast(float, v.y & 0xFFFF0000u);
            ax[k] = fmaf(v0, m, ax[k]);
            ay[k] = fmaf(v1, m, ay[k]);
            az[k] = fmaf(v2, m, az[k]);
            aw[k] = fmaf(v3, m, aw[k]);
        }
    }
    float tx = (ax[0] + ax[1]) + (ax[2] + ax[3]);
    float ty = (ay[0] + ay[1]) + (ay[2] + ay[3]);
    float tz = (az[0] + az[1]) + (az[2] + az[3]);
    float tw = (aw[0] + aw[1]) + (aw[2] + aw[3]);
    tx += __shfl_xor(tx, 32);
    ty += __shfl_xor(ty, 32);
    tz += __shfl_xor(tz, 32);
    tw += __shfl_xor(tw, 32);

    if (e == 0) {
        ushort4 sh = *(const ushort4*)&th[(size_t)node * HID + c * 4];
        float4 b4  = *(const float4*)&bias[c * 4];
        float ox = (tx + bf2f(sh.x)) * dn + b4.x;
        float oy = (ty + bf2f(sh.y)) * dn + b4.y;
        float oz = (tz + bf2f(sh.z)) * dn + b4.z;
        float ow = (tw + bf2f(sh.w)) * dn + b4.w;
        if (mode == 1) {
            ox = fmaxf(ox, 0.f); oy = fmaxf(oy, 0.f);
            oz = fmaxf(oz, 0.f); ow = fmaxf(ow, 0.f);
            unsigned short hx = f2bf(ox), hy = f2bf(oy), hz = f2bf(oz), hw = f2bf(ow);
            ushort4 vh; vh.x = hx; vh.y = hy; vh.z = hz; vh.w = hw;
            ushort4 vl;
            vl.x = f2bf(ox - bf2f(hx)); vl.y = f2bf(oy - bf2f(hy));
            vl.z = f2bf(oz - bf2f(hz)); vl.w = f2bf(ow - bf2f(hw));
            *(ushort4*)&hh[(size_t)node * HID + c * 4] = vh;
            *(ushort4*)&hl[(size_t)node * HID + c * 4] = vl;
        } else {
            float4 o = make_float4(ox, oy, oz, ow);
            *(float4*)&hout[(size_t)node * HID + c * 4] = o;
        }
    }
}

// ---- pool (gen-mean p=2) + FF head, one block per graph --------------------
__global__ __launch_bounds__(256) void k_poolff(const float* __restrict__ h,
                                                const int* __restrict__ batch,
                                                const float* __restrict__ Wf0,
                                                const float* __restrict__ bf0,
                                                const float* __restrict__ Wf1,
                                                const float* __restrict__ bf1,
                                                float* __restrict__ out) {
    __shared__ float smx[4][64], smy[4][64];
    __shared__ float row[128], zrow[128];
    __shared__ int bnd[2];
    int g = blockIdx.x;
    int t = threadIdx.x;
    if (t < 2) {
        int target = g + t;
        int lo = 0, hi = N_NODES;
        while (lo < hi) {
            int mid = (lo + hi) >> 1;
            if (batch[mid] < target) lo = mid + 1; else hi = mid;
        }
        bnd[t] = lo;
    }
    __syncthreads();
    int beg = bnd[0], end = bnd[1];

    int c = t & 63, slot = t >> 6;
    float sx = 0.f, sy = 0.f;
    for (int n = beg + slot; n < end; n += 4) {
        float2 v = *(const float2*)&h[(size_t)n * HID + c * 2];
        sx += signpow(v.x, false);
        sy += signpow(v.y, false);
    }
    smx[slot][c] = sx; smy[slot][c] = sy;
    __syncthreads();
    if (slot == 0) {
        sx = (smx[0][c] + smx[1][c]) + (smx[2][c] + smx[3][c]);
        sy = (smy[0][c] + smy[1][c]) + (smy[2][c] + smy[3][c]);
        float cnt = fmaxf((float)(end - beg), 1.0f);
        row[c * 2]     = fmaxf(signpow(sx / cnt, true), 0.f);
        row[c * 2 + 1] = fmaxf(signpow(sy / cnt, true), 0.f);
    }
    __syncthreads();
    if (t < 128) {
        float acc = bf0[t];
        #pragma unroll 8
        for (int k = 0; k < 128; k++) acc = fmaf(row[k], Wf0[k * 128 + t], acc);
        zrow[t] = fmaxf(acc, 0.f);
    }
    __syncthreads();
    if (t < OUT_DIM) {
        float a2 = bf1[t];
        #pragma unroll 8
        for (int k = 0; k < 128; k++) a2 = fmaf(zrow[k], Wf1[k * OUT_DIM + t], a2);
        out[g * OUT_DIM + t] = a2;
    }
}

// ---------------------------------------------------------------------------
static inline size_t align256(size_t x) { return (x + 255) & ~(size_t)255; }

extern "C" void kernel_launch(void* const* d_in, const int* in_sizes, int n_in,
                              void* d_out, int out_size, void* d_ws, size_t ws_size,
                              hipStream_t stream) {
    const float* x     = (const float*)d_in[0];
    const int*   ei    = (const int*)d_in[1];
    const int*   batch = (const int*)d_in[2];
    const float* W0  = (const float*)d_in[3];  const float* b0  = (const float*)d_in[4];
    const float* W1  = (const float*)d_in[5];  const float* b1  = (const float*)d_in[6];
    const float* W2  = (const float*)d_in[7];  const float* b2  = (const float*)d_in[8];
    const float* Wf0 = (const float*)d_in[9];  const float* bf0 = (const float*)d_in[10];
    const float* Wf1 = (const float*)d_in[11]; const float* bf1 = (const float*)d_in[12];
    float* out = (float*)d_out;

    char* p = (char*)d_ws;
    unsigned short* th = (unsigned short*)p; p += align256((size_t)M_PAD * HID * 2);
    short* bufAh = (short*)p; p += align256((size_t)M_PAD * HID * 2);
    short* bufAl = (short*)p; p += align256((size_t)M_PAD * HID * 2);
    short* bufBh = (short*)p; p += align256((size_t)M_PAD * HID * 2);
    short* bufBl = (short*)p; p += align256((size_t)M_PAD * HID * 2);
    float* h     = (float*)bufBh;   // aliases bufBh+bufBl (contiguous), live only after layer2
    unsigned* ebuf = (unsigned*)p; p += align256((size_t)NBUCK * BUCKCAP * 4);
    int*   gcnt    = (int*)p;   p += align256((size_t)NBUCK * 4);
    int*   offs    = (int*)p;   p += align256((size_t)(N_NODES + 1) * 4);
    int*   csr     = (int*)p;   p += align256((size_t)N_EDGES * 4);
    float* dis     = (float*)p; p += align256((size_t)N_NODES * 4);
    short* Wth     = (short*)p; p += align256((size_t)3 * HID * HID * 2);
    short* Wtl     = (short*)p; p += align256((size_t)3 * HID * HID * 2);

    hipMemsetAsync(gcnt, 0, (size_t)NBUCK * 4, stream);

    k_bucketize<<<ABLOCKS, 256, 0, stream>>>(ei, gcnt, ebuf);
    k_csr      <<<NBUCK, 256, 0, stream>>>(ebuf, gcnt, offs, dis, csr);

    dim3 wg(64, 3);
    k_wsplit3<<<wg, 256, 0, stream>>>(W0, W1, W2, Wth, Wtl);

    int agg_blocks = (N_NODES + 3) / 4;

    // layer 0: GEMM reads fp32 x directly (hi/lo split in staging)
    k_gemm_mfma<1><<<GEMM_GRID, 256, 0, stream>>>(x, nullptr, Wth, Wtl, th, dis);
    k_agg<<<agg_blocks, 256, 0, stream>>>(th, offs, csr, dis, b0,
                                          nullptr, bufBh, bufBl, 1);
    // layer 1
    k_gemm_mfma<0><<<GEMM_GRID, 256, 0, stream>>>(bufBh, bufBl,
                                                  Wth + HID * HID, Wtl + HID * HID, th, dis);
    k_agg<<<agg_blocks, 256, 0, stream>>>(th, offs, csr, dis, b1,
                                          nullptr, bufAh, bufAl, 1);
    // layer 2 (no relu, fp32 out for pooling)
    k_gemm_mfma<0><<<GEMM_GRID, 256, 0, stream>>>(bufAh, bufAl,
                                                  Wth + 2 * HID * HID, Wtl + 2 * HID * HID, th, dis);
    k_agg<<<agg_blocks, 256, 0, stream>>>(th, offs, csr, dis, b2,
                                          h, nullptr, nullptr, 0);

    k_poolff<<<NUM_GRAPHS, 256, 0, stream>>>(h, batch, Wf0, bf0, Wf1, bf1, out);
}